// Round 2
// baseline (1647.294 us; speedup 1.0000x reference)
//
#include <hip/hip_runtime.h>
#include <hip/hip_bf16.h>
#include <math.h>

#define N_NODES 10000
#define NPAD    10048
#define IN_DIM  144
#define TD      256
#define OD      700
#define TOPK    5

// ---------------- kernel 1: BN partial sums (f64, deterministic) ----------------
__global__ void bn_partial(const float* __restrict__ H, double* __restrict__ part){
    int c = threadIdx.x;
    int b = blockIdx.x;
    if (c >= IN_DIM) return;
    int r0 = b * 250;
    double s = 0.0, q = 0.0;
    for (int r = r0; r < r0 + 250; ++r){
        double v = (double)H[r*IN_DIM + c];
        s += v; q += v*v;
    }
    part[b*288 + c]       = s;
    part[b*288 + 144 + c] = q;
}

__global__ void bn_finish(const double* __restrict__ part, double* __restrict__ stats){
    int c = threadIdx.x;
    if (c >= 288) return;
    double s = 0.0;
    for (int b = 0; b < 40; ++b) s += part[b*288 + c];
    stats[c] = s;
}

// ---------------- kernel 2: BN + theta projection + row normalize ----------------
// Mirrors the f32 reference pipeline: Hn rounded to f32 BEFORE the theta GEMM,
// Hx rounded to f32 BEFORE the norm, Xn = f32. (Each stage computed in f64 and
// rounded once -> within ~1 ulp of numpy's f32 value.)
__global__ __launch_bounds__(256) void theta_kernel(
    const float* __restrict__ H, const float* __restrict__ gam, const float* __restrict__ bet,
    const float* __restrict__ Wt, const float* __restrict__ bt, const double* __restrict__ stats,
    float* __restrict__ Hn32, float* __restrict__ Xn32)
{
    __shared__ double hn[4][IN_DIM];
    __shared__ double red[4][4];
    __shared__ double invs[4];
    int tid = threadIdx.x;
    int r0 = blockIdx.x * 4;

    if (tid < IN_DIM){
        int c = tid;
        double mean  = stats[c] * (1.0/10000.0);
        double var   = stats[144+c] * (1.0/10000.0) - mean*mean;
        double scale = (1.0/sqrt(var + 1e-5)) * (double)gam[c];
        double bb    = (double)bet[c];
        for (int r = 0; r < 4; ++r){
            int row = r0 + r;
            float vf = 0.0f;
            if (row < N_NODES){
                double v = ((double)H[row*IN_DIM + c] - mean)*scale + bb;
                vf = (float)v;
                Hn32[row*IN_DIM + c] = vf;
            }
            hn[r][c] = (double)vf;   // f32-rounded value, widened
        }
    }
    __syncthreads();

    int j = tid; // 0..255 == THETA_DIM
    double a0,a1,a2,a3;
    a0=a1=a2=a3=(double)bt[j];
    for (int k = 0; k < IN_DIM; ++k){
        double w = (double)Wt[k*TD + j];
        a0 += hn[0][k]*w; a1 += hn[1][k]*w; a2 += hn[2][k]*w; a3 += hn[3][k]*w;
    }
    // round Hx to f32 (reference does the GEMM in f32), then norm over f32 values
    float hx0=(float)a0, hx1=(float)a1, hx2=(float)a2, hx3=(float)a3;
    double n0=(double)hx0*(double)hx0, n1=(double)hx1*(double)hx1,
           n2=(double)hx2*(double)hx2, n3=(double)hx3*(double)hx3;
    #pragma unroll
    for (int off=32; off>0; off>>=1){
        n0 += __shfl_down(n0, off);
        n1 += __shfl_down(n1, off);
        n2 += __shfl_down(n2, off);
        n3 += __shfl_down(n3, off);
    }
    int lane = tid & 63, wave = tid >> 6;
    if (lane == 0){ red[0][wave]=n0; red[1][wave]=n1; red[2][wave]=n2; red[3][wave]=n3; }
    __syncthreads();
    if (tid < 4){
        double s = red[tid][0]+red[tid][1]+red[tid][2]+red[tid][3];
        invs[tid] = 1.0 / fmax(sqrt(s), 1e-12);
    }
    __syncthreads();

    float hx[4] = {hx0,hx1,hx2,hx3};
    #pragma unroll
    for (int r = 0; r < 4; ++r){
        int row = r0 + r;
        if (row < N_NODES){
            Xn32[(size_t)row*TD + j] = (float)((double)hx[r]*invs[r]);
        } else {
            Xn32[(size_t)row*TD + j] = 0.0f;  // padded rows -> zero (never selected)
        }
    }
}

// ---------------- kernel 3: G = Hn @ W_out + b_out (fp32) ----------------
__global__ __launch_bounds__(256) void gproj(const float* __restrict__ Hn32,
    const float* __restrict__ Wo, const float* __restrict__ bo, float* __restrict__ G)
{
    __shared__ float hn[16*IN_DIM];
    int tid = threadIdx.x;
    int r0 = blockIdx.x * 16;
    for (int t = tid; t < 16*IN_DIM; t += 256) hn[t] = Hn32[(size_t)r0*IN_DIM + t];
    __syncthreads();
    for (int col = tid; col < OD; col += 256){
        float b = bo[col];
        float acc[16];
        #pragma unroll
        for (int r=0;r<16;++r) acc[r]=b;
        for (int k=0;k<IN_DIM;++k){
            float w = Wo[k*OD + col];
            #pragma unroll
            for (int r=0;r<16;++r) acc[r] = fmaf(hn[r*IN_DIM+k], w, acc[r]);
        }
        #pragma unroll
        for (int r=0;r<16;++r) G[(size_t)(r0+r)*OD + col] = acc[r];
    }
}

// ---------------- kernel 4: fused cos GEMM + per-row running top-k (phase 1, fp32) ----------------
#define TI 64
#define TJ 64
#define LDK 68   // 64 + 4 pad -> conflict-free b128 LDS reads

__global__ __launch_bounds__(256,3) void cos_topk(const float* __restrict__ Xn32,
                                                  int* __restrict__ pidx)
{
    __shared__ float smem[10240]; // 40 KB: tiles, then reused for the merge phase
    float* At = smem;             // [64][68]
    float* Bt = smem + 64*LDK;    // [64][68]

    int bid   = blockIdx.x;
    int it    = bid >> 2;
    int chunk = bid & 3;
    int i0    = it * TI;
    int jbeg  = chunk * 2560;
    int jend  = min(jbeg + 2560, N_NODES);
    int tid = threadIdx.x;
    int tx = tid & 15, ty = tid >> 4;

    float tv[4][5];
    int   tix[4][5];
    #pragma unroll
    for (int a=0;a<4;++a){
        #pragma unroll
        for (int s=0;s<5;++s){ tv[a][s] = -2.0f; tix[a][s] = 0x7fffffff; }
    }

    int srow = tid >> 4;   // staging: row-in-pass
    int sf4  = tid & 15;   // staging: float4 index within 64-float k-chunk

    for (int j0 = jbeg; j0 < jend; j0 += TJ){
        float acc[4][4];
        #pragma unroll
        for (int a=0;a<4;++a){
            #pragma unroll
            for (int b=0;b<4;++b) acc[a][b]=0.f;
        }

        for (int kc = 0; kc < TD; kc += 64){
            __syncthreads();
            #pragma unroll
            for (int p = 0; p < 4; ++p){
                int r = p*16 + srow;
                float4 va = *(const float4*)(&Xn32[(size_t)(i0+r)*TD + kc + sf4*4]);
                *(float4*)(&At[r*LDK + sf4*4]) = va;
                float4 vb = *(const float4*)(&Xn32[(size_t)(j0+r)*TD + kc + sf4*4]);
                *(float4*)(&Bt[r*LDK + sf4*4]) = vb;
            }
            __syncthreads();
            #pragma unroll 4
            for (int kq = 0; kq < 16; ++kq){
                float4 af[4], bf[4];
                #pragma unroll
                for (int a=0;a<4;++a) af[a] = *(const float4*)(&At[(ty+16*a)*LDK + kq*4]);
                #pragma unroll
                for (int b=0;b<4;++b) bf[b] = *(const float4*)(&Bt[(tx+16*b)*LDK + kq*4]);
                #pragma unroll
                for (int a=0;a<4;++a){
                    #pragma unroll
                    for (int b=0;b<4;++b){
                        acc[a][b] = fmaf(af[a].x, bf[b].x, acc[a][b]);
                        acc[a][b] = fmaf(af[a].y, bf[b].y, acc[a][b]);
                        acc[a][b] = fmaf(af[a].z, bf[b].z, acc[a][b]);
                        acc[a][b] = fmaf(af[a].w, bf[b].w, acc[a][b]);
                    }
                }
            }
        }

        // running top-5 per (row, thread-column); j scanned ascending -> stable ties
        #pragma unroll
        for (int b=0;b<4;++b){
            int j = j0 + tx + 16*b;
            bool ok = (j < jend);
            #pragma unroll
            for (int a=0;a<4;++a){
                float v = acc[a][b];
                if (ok && (v > tv[a][4] || (v == tv[a][4] && j < tix[a][4]))){
                    tv[a][4] = v; tix[a][4] = j;
                    #pragma unroll
                    for (int s=4;s>0;--s){
                        bool sw = (tv[a][s] > tv[a][s-1]) ||
                                  (tv[a][s]==tv[a][s-1] && tix[a][s] < tix[a][s-1]);
                        float fv = tv[a][s]; int fi = tix[a][s];
                        if (sw){
                            tv[a][s]=tv[a][s-1]; tix[a][s]=tix[a][s-1];
                            tv[a][s-1]=fv;       tix[a][s-1]=fi;
                        }
                    }
                }
            }
        }
    }

    // merge 16 thread-columns x top5 -> per-row top-16 for this chunk
    __syncthreads();
    float* mv = smem;                 // [64][80]
    int*   mi = (int*)(smem + 5120);  // [64][80]
    #pragma unroll
    for (int a=0;a<4;++a){
        int row = ty + 16*a;
        int base = row*80 + tx*5;
        #pragma unroll
        for (int s=0;s<5;++s){ mv[base+s] = tv[a][s]; mi[base+s] = tix[a][s]; }
    }
    __syncthreads();
    if (tid < 64){
        int gi = i0 + tid;
        if (gi < N_NODES){
            float bv[16]; int bi[16];
            #pragma unroll
            for (int s=0;s<16;++s){ bv[s]=-3.0f; bi[s]=0x7fffffff; }
            int rb = tid*80;
            for (int c2=0;c2<80;++c2){
                float v = mv[rb+c2]; int ix = mi[rb+c2];
                if (v > bv[15] || (v==bv[15] && ix < bi[15])){
                    bv[15]=v; bi[15]=ix;
                    #pragma unroll
                    for (int s=15;s>0;--s){
                        bool sw = (bv[s] > bv[s-1]) || (bv[s]==bv[s-1] && bi[s]<bi[s-1]);
                        float fv=bv[s]; int fi=bi[s];
                        if (sw){ bv[s]=bv[s-1]; bi[s]=bi[s-1]; bv[s-1]=fv; bi[s-1]=fi; }
                    }
                }
            }
            #pragma unroll
            for (int s=0;s<16;++s) pidx[(size_t)gi*64 + chunk*16 + s] = bi[s];
        }
    }
}

// ---------------- kernel 5: refinement — exact cos of f32 Xn, f32 A-chain keys ----------------
// Selection key replicates the reference's f32 pipeline: cos rounded to f32,
// clipped, acosf/expf/sigmoid in f32. Equal f32 keys tie-break by LOWER index
// (lax.top_k semantics). This matches the golden's behavior on near-ties that
// collapse to equal f32 A values.
__global__ __launch_bounds__(64) void refine(const float* __restrict__ Xn32,
    const int* __restrict__ pidx, float* __restrict__ topA, int* __restrict__ topI,
    float* __restrict__ dinv)
{
    __shared__ float xi[TD];
    int row = blockIdx.x;
    int l = threadIdx.x;
    for (int k = l; k < TD; k += 64) xi[k] = Xn32[(size_t)row*TD + k];
    __syncthreads();

    int j = pidx[(size_t)row*64 + l];
    const float* xj = &Xn32[(size_t)j*TD];
    double s = 0.0;
    for (int k = 0; k < TD; k += 4){
        float4 b = *(const float4*)(&xj[k]);
        s += (double)xi[k+0]*(double)b.x;
        s += (double)xi[k+1]*(double)b.y;
        s += (double)xi[k+2]*(double)b.z;
        s += (double)xi[k+3]*(double)b.w;
    }
    float cos32 = (float)s;
    cos32 = fminf(fmaxf(cos32, -1.0f), 1.0f);
    float sam = acosf(cos32);
    float e   = expf(-0.2f*sam);
    float key = 1.0f/(1.0f + expf(-e));   // sigmoid; > 0.5 so clip(0.1) is a no-op

    double dsum = 0.0;
    for (int t = 0; t < TOPK; ++t){
        float v = key; int ix = j;
        #pragma unroll
        for (int off=32; off>0; off>>=1){
            float ov = __shfl_xor(v, off);
            int oix  = __shfl_xor(ix, off);
            if (ov > v || (ov == v && oix < ix)){ v = ov; ix = oix; }
        }
        dsum += (double)v;
        if (l == 0){ topA[row*TOPK + t] = v; topI[row*TOPK + t] = ix; }
        if (j == ix) key = -1.0f;  // remove selected candidate (all real keys > 0.6)
    }
    if (l == 0) dinv[row] = (float)(1.0/sqrt(dsum));
}

// ---------------- kernel 6: out = lrelu( A_hat(5-sparse) @ G ) ----------------
__global__ __launch_bounds__(256) void outk(const float* __restrict__ G,
    const float* __restrict__ topA, const int* __restrict__ topI,
    const float* __restrict__ dinv, float* __restrict__ out)
{
    __shared__ float w[TOPK];
    __shared__ int   jj[TOPK];
    int row = blockIdx.x, tid = threadIdx.x;
    if (tid < TOPK){
        int j = topI[row*TOPK + tid];
        jj[tid] = j;
        w[tid]  = topA[row*TOPK + tid] * dinv[row] * dinv[j];
    }
    __syncthreads();
    for (int col = tid; col < OD; col += 256){
        float acc = 0.f;
        #pragma unroll
        for (int m=0;m<TOPK;++m) acc = fmaf(w[m], G[(size_t)jj[m]*OD + col], acc);
        out[(size_t)row*OD + col] = acc >= 0.f ? acc : 0.01f*acc;
    }
}

// ---------------- kernel 7: scatter A values (after memset of A region) ----------------
__global__ void scatter(const float* __restrict__ topA, const int* __restrict__ topI,
                        float* __restrict__ Aout)
{
    int t = blockIdx.x*256 + threadIdx.x;
    if (t >= N_NODES*TOPK) return;
    int row = t / TOPK;
    Aout[(size_t)row*N_NODES + topI[t]] = topA[t];
}

extern "C" void kernel_launch(void* const* d_in, const int* in_sizes, int n_in,
                              void* d_out, int out_size, void* d_ws, size_t ws_size,
                              hipStream_t stream)
{
    const float* H   = (const float*)d_in[0];
    const float* gam = (const float*)d_in[1];
    const float* bet = (const float*)d_in[2];
    const float* Wt  = (const float*)d_in[3];
    const float* bt  = (const float*)d_in[4];
    const float* Wo  = (const float*)d_in[5];
    const float* bo  = (const float*)d_in[6];

    float* out  = (float*)d_out;
    float* Aout = out + (size_t)N_NODES*OD;   // + 7,000,000 floats

    // scratch carved out of the A region of d_out (all consumed before the memset)
    float*  Xn32 = Aout;                          // 10048*256  = 2,572,288 f
    float*  Hn32 = Aout + 2572288;                // 10000*144  = 1,440,000 f
    float*  G    = Aout + 4012288;                // 10000*700  = 7,000,000 f
    int*    pidx = (int*)(Aout + 11012288);       // 10000*64   =   640,000 i
    // ends at 11,652,288 floats < 100,000,000

    // small persistent scratch in ws (needed after the A memset)
    double* bn_part  = (double*)d_ws;             // 40*288 f64
    double* bn_stats = bn_part + 40*288;          // 288 f64
    float*  topA  = (float*)(bn_stats + 288);     // 50,000 f32
    int*    topI  = (int*)(topA + 50000);         // 50,000 i32
    float*  dinvp = (float*)(topI + 50000);       // 10,000 f32

    bn_partial <<<40, 192, 0, stream>>>(H, bn_part);
    bn_finish  <<<1, 320, 0, stream>>>(bn_part, bn_stats);
    theta_kernel<<<NPAD/4, 256, 0, stream>>>(H, gam, bet, Wt, bt, bn_stats, Hn32, Xn32);
    gproj      <<<N_NODES/16, 256, 0, stream>>>(Hn32, Wo, bo, G);
    cos_topk   <<<157*4, 256, 0, stream>>>(Xn32, pidx);
    refine     <<<N_NODES, 64, 0, stream>>>(Xn32, pidx, topA, topI, dinvp);
    outk       <<<N_NODES, 256, 0, stream>>>(G, topA, topI, dinvp, out);
    hipMemsetAsync(Aout, 0, (size_t)N_NODES*N_NODES*sizeof(float), stream);
    scatter    <<<(N_NODES*TOPK + 255)/256, 256, 0, stream>>>(topA, topI, Aout);
}

// Round 3
// 1094.018 us; speedup vs baseline: 1.5057x; 1.5057x over previous
//
#include <hip/hip_runtime.h>
#include <hip/hip_bf16.h>
#include <math.h>

#define N_NODES 10000
#define NPAD2   10240     // padded row count for the cos GEMM (multiple of 256)
#define IN_DIM  144
#define TD      256
#define KE      768       // extended K: [hi|hi|lo] . [hi|lo|hi]
#define OD      700
#define TOPK    5

typedef __attribute__((ext_vector_type(8))) short short8v;
typedef __attribute__((ext_vector_type(4))) float f32x4;

__device__ inline unsigned short f32_to_bf16_rne(float f){
    unsigned int u = __float_as_uint(f);
    unsigned int r = u + 0x7fffu + ((u >> 16) & 1u);
    return (unsigned short)(r >> 16);
}
__device__ inline float bf16_bits_to_f32(unsigned short h){
    unsigned int u = ((unsigned int)h) << 16;
    return __uint_as_float(u);
}

// ---------------- kernel 1: BN partial sums (f64, deterministic) ----------------
__global__ void bn_partial(const float* __restrict__ H, double* __restrict__ part){
    int c = threadIdx.x;
    int b = blockIdx.x;
    if (c >= IN_DIM) return;
    int r0 = b * 250;
    double s = 0.0, q = 0.0;
    for (int r = r0; r < r0 + 250; ++r){
        double v = (double)H[r*IN_DIM + c];
        s += v; q += v*v;
    }
    part[b*288 + c]       = s;
    part[b*288 + 144 + c] = q;
}

__global__ void bn_finish(const double* __restrict__ part, double* __restrict__ stats){
    int c = threadIdx.x;
    if (c >= 288) return;
    double s = 0.0;
    for (int b = 0; b < 40; ++b) s += part[b*288 + c];
    stats[c] = s;
}

// ---------------- kernel 2: BN + theta projection + row normalize + bf16 hi/lo split ----------------
__global__ __launch_bounds__(256) void theta_kernel(
    const float* __restrict__ H, const float* __restrict__ gam, const float* __restrict__ bet,
    const float* __restrict__ Wt, const float* __restrict__ bt, const double* __restrict__ stats,
    float* __restrict__ Hn32, float* __restrict__ Xn32,
    unsigned short* __restrict__ Xa, unsigned short* __restrict__ Xb)
{
    __shared__ double hn[4][IN_DIM];
    __shared__ double red[4][4];
    __shared__ double invs[4];
    int tid = threadIdx.x;
    int r0 = blockIdx.x * 4;

    if (tid < IN_DIM){
        int c = tid;
        double mean  = stats[c] * (1.0/10000.0);
        double var   = stats[144+c] * (1.0/10000.0) - mean*mean;
        double scale = (1.0/sqrt(var + 1e-5)) * (double)gam[c];
        double bb    = (double)bet[c];
        for (int r = 0; r < 4; ++r){
            int row = r0 + r;
            float vf = 0.0f;
            if (row < N_NODES){
                double v = ((double)H[row*IN_DIM + c] - mean)*scale + bb;
                vf = (float)v;
                Hn32[row*IN_DIM + c] = vf;
            }
            hn[r][c] = (double)vf;   // f32-rounded value, widened
        }
    }
    __syncthreads();

    int j = tid; // 0..255 == THETA_DIM
    double a0,a1,a2,a3;
    a0=a1=a2=a3=(double)bt[j];
    for (int k = 0; k < IN_DIM; ++k){
        double w = (double)Wt[k*TD + j];
        a0 += hn[0][k]*w; a1 += hn[1][k]*w; a2 += hn[2][k]*w; a3 += hn[3][k]*w;
    }
    float hx0=(float)a0, hx1=(float)a1, hx2=(float)a2, hx3=(float)a3;
    double n0=(double)hx0*(double)hx0, n1=(double)hx1*(double)hx1,
           n2=(double)hx2*(double)hx2, n3=(double)hx3*(double)hx3;
    #pragma unroll
    for (int off=32; off>0; off>>=1){
        n0 += __shfl_down(n0, off);
        n1 += __shfl_down(n1, off);
        n2 += __shfl_down(n2, off);
        n3 += __shfl_down(n3, off);
    }
    int lane = tid & 63, wave = tid >> 6;
    if (lane == 0){ red[0][wave]=n0; red[1][wave]=n1; red[2][wave]=n2; red[3][wave]=n3; }
    __syncthreads();
    if (tid < 4){
        double s = red[tid][0]+red[tid][1]+red[tid][2]+red[tid][3];
        invs[tid] = 1.0 / fmax(sqrt(s), 1e-12);
    }
    __syncthreads();

    float hx[4] = {hx0,hx1,hx2,hx3};
    #pragma unroll
    for (int r = 0; r < 4; ++r){
        int row = r0 + r;
        float xn = 0.0f;
        if (row < N_NODES) xn = (float)((double)hx[r]*invs[r]);
        Xn32[(size_t)row*TD + j] = xn;
        unsigned short hu = f32_to_bf16_rne(xn);
        float hf = bf16_bits_to_f32(hu);
        unsigned short lu = f32_to_bf16_rne(xn - hf);
        size_t base = (size_t)row*KE;
        Xa[base +       j] = hu;
        Xa[base + 256 + j] = hu;
        Xa[base + 512 + j] = lu;
        Xb[base +       j] = hu;
        Xb[base + 256 + j] = lu;
        Xb[base + 512 + j] = hu;
    }
}

// ---------------- kernel 3: G = Hn @ W_out + b_out (fp32) ----------------
__global__ __launch_bounds__(256) void gproj(const float* __restrict__ Hn32,
    const float* __restrict__ Wo, const float* __restrict__ bo, float* __restrict__ G)
{
    __shared__ float hn[16*IN_DIM];
    int tid = threadIdx.x;
    int r0 = blockIdx.x * 16;
    for (int t = tid; t < 16*IN_DIM; t += 256) hn[t] = Hn32[(size_t)r0*IN_DIM + t];
    __syncthreads();
    for (int col = tid; col < OD; col += 256){
        float b = bo[col];
        float acc[16];
        #pragma unroll
        for (int r=0;r<16;++r) acc[r]=b;
        for (int k=0;k<IN_DIM;++k){
            float w = Wo[k*OD + col];
            #pragma unroll
            for (int r=0;r<16;++r) acc[r] = fmaf(hn[r*IN_DIM+k], w, acc[r]);
        }
        #pragma unroll
        for (int r=0;r<16;++r) G[(size_t)(r0+r)*OD + col] = acc[r];
    }
}

// ---------------- kernel 4: MFMA cos GEMM (bf16 hi/lo, K=768) + per-row top-k ----------------
#define TI  64
#define TJc 256
#define LDT 72     // shorts per LDS tile row (64 + 8 pad): conflict-free b128 frag reads
#define CHUNK 2560

__global__ __launch_bounds__(256,2) void cos_topk(const unsigned short* __restrict__ Xa,
                                                  const unsigned short* __restrict__ Xb,
                                                  int* __restrict__ pidx)
{
    __shared__ short lds[23040];              // 46080 B
    short* Ald = lds;                         // [64][72]   (i rows)
    short* Bld = lds + TI*LDT;                // [256][72]  (j rows)

    int bid   = blockIdx.x;
    int it    = bid >> 2;
    int chunk = bid & 3;
    int i0    = it * TI;
    int jbeg  = chunk * CHUNK;

    int tid  = threadIdx.x;
    int lane = tid & 63, w = tid >> 6;
    int l15  = lane & 15, l4 = lane >> 4;

    float tv[4][5];
    int   tix[4][5];
    #pragma unroll
    for (int n=0;n<4;++n){
        #pragma unroll
        for (int s=0;s<5;++s){ tv[n][s] = -2.0f; tix[n][s] = 0x7fffffff; }
    }

    for (int jt = 0; jt < CHUNK; jt += TJc){
        int j0 = jbeg + jt;
        f32x4 acc[4][4];
        #pragma unroll
        for (int m=0;m<4;++m){
            #pragma unroll
            for (int n=0;n<4;++n) acc[m][n] = (f32x4){0.f,0.f,0.f,0.f};
        }

        for (int kc = 0; kc < KE; kc += 64){
            __syncthreads();
            // stage A-tile: 64 rows x 64 shorts (2 x 16B per thread)
            #pragma unroll
            for (int p=0;p<2;++p){
                int idx = tid + p*256;
                int r = idx >> 3, s = idx & 7;
                short8v v = *(const short8v*)(&Xa[(size_t)(i0+r)*KE + kc + s*8]);
                *(short8v*)(&Ald[r*LDT + s*8]) = v;
            }
            // stage B-tile: 256 rows x 64 shorts (8 x 16B per thread)
            #pragma unroll
            for (int p=0;p<8;++p){
                int idx = tid + p*256;
                int r = idx >> 3, s = idx & 7;
                short8v v = *(const short8v*)(&Xb[(size_t)(j0+r)*KE + kc + s*8]);
                *(short8v*)(&Bld[r*LDT + s*8]) = v;
            }
            __syncthreads();
            // wave w: A-operand = j rows [w*64, w*64+64), B-operand = i rows [0,64)
            #pragma unroll
            for (int ks=0; ks<2; ++ks){
                short8v af[4], bf[4];
                #pragma unroll
                for (int m=0;m<4;++m)
                    af[m] = *(const short8v*)(&Bld[(w*64 + m*16 + l15)*LDT + ks*32 + l4*8]);
                #pragma unroll
                for (int n=0;n<4;++n)
                    bf[n] = *(const short8v*)(&Ald[(n*16 + l15)*LDT + ks*32 + l4*8]);
                #pragma unroll
                for (int m=0;m<4;++m){
                    #pragma unroll
                    for (int n=0;n<4;++n){
                        acc[m][n] = __builtin_amdgcn_mfma_f32_16x16x32_bf16(af[m], bf[n], acc[m][n], 0, 0, 0);
                    }
                }
            }
        }

        // fold tile into running per-lane top-5 (C: row=j=m*16+l4*4+q, col=i=n*16+l15)
        #pragma unroll
        for (int m=0;m<4;++m){
            int jb = j0 + w*64 + m*16 + l4*4;
            #pragma unroll
            for (int q=0;q<4;++q){
                int j = jb + q;
                #pragma unroll
                for (int n=0;n<4;++n){
                    float v = acc[m][n][q];
                    if (v > tv[n][4] || (v == tv[n][4] && j < tix[n][4])){
                        tv[n][4] = v; tix[n][4] = j;
                        #pragma unroll
                        for (int s=4;s>0;--s){
                            bool sw = (tv[n][s] > tv[n][s-1]) ||
                                      (tv[n][s]==tv[n][s-1] && tix[n][s] < tix[n][s-1]);
                            float fv = tv[n][s]; int fi = tix[n][s];
                            if (sw){
                                tv[n][s]=tv[n][s-1]; tix[n][s]=tix[n][s-1];
                                tv[n][s-1]=fv;       tix[n][s-1]=fi;
                            }
                        }
                    }
                }
            }
        }
    }

    // merge: 16 lists (4 waves x 4 lane-groups) x top5 -> per-row top-16 for this chunk
    __syncthreads();
    float* mv = (float*)lds;              // [64][80]  20480 B
    int*   mi = (int*)(lds + 10240);      // [64][80]  20480 B
    #pragma unroll
    for (int n=0;n<4;++n){
        int ilocal = n*16 + l15;
        int list   = w*4 + l4;
        int base   = ilocal*80 + list*5;
        #pragma unroll
        for (int s=0;s<5;++s){ mv[base+s] = tv[n][s]; mi[base+s] = tix[n][s]; }
    }
    __syncthreads();
    if (tid < 64){
        int gi = i0 + tid;
        if (gi < N_NODES){
            float bv[16]; int bi[16];
            #pragma unroll
            for (int s=0;s<16;++s){ bv[s]=-3.0f; bi[s]=0x7fffffff; }
            int rb = tid*80;
            for (int c2=0;c2<80;++c2){
                float v = mv[rb+c2]; int ix = mi[rb+c2];
                if (v > bv[15] || (v==bv[15] && ix < bi[15])){
                    bv[15]=v; bi[15]=ix;
                    #pragma unroll
                    for (int s=15;s>0;--s){
                        bool sw = (bv[s] > bv[s-1]) || (bv[s]==bv[s-1] && bi[s]<bi[s-1]);
                        float fv=bv[s]; int fi=bi[s];
                        if (sw){ bv[s]=bv[s-1]; bi[s]=bi[s-1]; bv[s-1]=fv; bi[s-1]=fi; }
                    }
                }
            }
            #pragma unroll
            for (int s=0;s<16;++s) pidx[(size_t)gi*64 + chunk*16 + s] = bi[s];
        }
    }
}

// ---------------- kernel 5: refinement — exact cos of f32 Xn, f32 A-chain keys ----------------
__global__ __launch_bounds__(64) void refine(const float* __restrict__ Xn32,
    const int* __restrict__ pidx, float* __restrict__ topA, int* __restrict__ topI,
    float* __restrict__ dinv)
{
    __shared__ float xi[TD];
    int row = blockIdx.x;
    int l = threadIdx.x;
    for (int k = l; k < TD; k += 64) xi[k] = Xn32[(size_t)row*TD + k];
    __syncthreads();

    int j  = pidx[(size_t)row*64 + l];
    int jc = j < N_NODES ? j : 0;
    const float* xj = &Xn32[(size_t)jc*TD];
    double s = 0.0;
    for (int k = 0; k < TD; k += 4){
        float4 b = *(const float4*)(&xj[k]);
        s += (double)xi[k+0]*(double)b.x;
        s += (double)xi[k+1]*(double)b.y;
        s += (double)xi[k+2]*(double)b.z;
        s += (double)xi[k+3]*(double)b.w;
    }
    float cos32 = (float)s;
    cos32 = fminf(fmaxf(cos32, -1.0f), 1.0f);
    float sam = acosf(cos32);
    float e   = expf(-0.2f*sam);
    float key = 1.0f/(1.0f + expf(-e));   // sigmoid; > 0.5 so clip(0.1) is a no-op
    if (j >= N_NODES) key = -1.0f;        // padded rows can never be selected

    double dsum = 0.0;
    for (int t = 0; t < TOPK; ++t){
        float v = key; int ix = j;
        #pragma unroll
        for (int off=32; off>0; off>>=1){
            float ov = __shfl_xor(v, off);
            int oix  = __shfl_xor(ix, off);
            if (ov > v || (ov == v && oix < ix)){ v = ov; ix = oix; }
        }
        dsum += (double)v;
        if (l == 0){ topA[row*TOPK + t] = v; topI[row*TOPK + t] = ix; }
        if (j == ix) key = -1.0f;  // remove selected candidate
    }
    if (l == 0) dinv[row] = (float)(1.0/sqrt(dsum));
}

// ---------------- kernel 6: out = lrelu( A_hat(5-sparse) @ G ) ----------------
__global__ __launch_bounds__(256) void outk(const float* __restrict__ G,
    const float* __restrict__ topA, const int* __restrict__ topI,
    const float* __restrict__ dinv, float* __restrict__ out)
{
    __shared__ float w[TOPK];
    __shared__ int   jj[TOPK];
    int row = blockIdx.x, tid = threadIdx.x;
    if (tid < TOPK){
        int j = topI[row*TOPK + tid];
        jj[tid] = j;
        w[tid]  = topA[row*TOPK + tid] * dinv[row] * dinv[j];
    }
    __syncthreads();
    for (int col = tid; col < OD; col += 256){
        float acc = 0.f;
        #pragma unroll
        for (int m=0;m<TOPK;++m) acc = fmaf(w[m], G[(size_t)jj[m]*OD + col], acc);
        out[(size_t)row*OD + col] = acc >= 0.f ? acc : 0.01f*acc;
    }
}

// ---------------- kernel 7: scatter A values (after memset of A region) ----------------
__global__ void scatter(const float* __restrict__ topA, const int* __restrict__ topI,
                        float* __restrict__ Aout)
{
    int t = blockIdx.x*256 + threadIdx.x;
    if (t >= N_NODES*TOPK) return;
    int row = t / TOPK;
    Aout[(size_t)row*N_NODES + topI[t]] = topA[t];
}

extern "C" void kernel_launch(void* const* d_in, const int* in_sizes, int n_in,
                              void* d_out, int out_size, void* d_ws, size_t ws_size,
                              hipStream_t stream)
{
    const float* H   = (const float*)d_in[0];
    const float* gam = (const float*)d_in[1];
    const float* bet = (const float*)d_in[2];
    const float* Wt  = (const float*)d_in[3];
    const float* bt  = (const float*)d_in[4];
    const float* Wo  = (const float*)d_in[5];
    const float* bo  = (const float*)d_in[6];

    float* out  = (float*)d_out;
    float* Aout = out + (size_t)N_NODES*OD;   // + 7,000,000 floats

    // scratch carved out of the A region of d_out (all consumed before the memset)
    float*          Xn32 = Aout;                               // 10240*256 = 2,621,440 f
    float*          Hn32 = Aout + 2621440;                     // 10000*144 = 1,440,000 f
    float*          G    = Aout + 4061440;                     // 10000*700 = 7,000,000 f
    unsigned short* Xa   = (unsigned short*)(Aout + 11061440); // 10240*768 us = 3,932,160 f
    unsigned short* Xb   = (unsigned short*)(Aout + 14993600); // 10240*768 us = 3,932,160 f
    int*            pidx = (int*)(Aout + 18925760);            // 10000*64 = 640,000 i
    // ends at 19,565,760 floats < 100,000,000

    // small persistent scratch in ws (needed after the A memset)
    double* bn_part  = (double*)d_ws;             // 40*288 f64
    double* bn_stats = bn_part + 40*288;          // 288 f64
    float*  topA  = (float*)(bn_stats + 288);     // 50,000 f32
    int*    topI  = (int*)(topA + 50000);         // 50,000 i32
    float*  dinvp = (float*)(topI + 50000);       // 10,000 f32

    bn_partial <<<40, 192, 0, stream>>>(H, bn_part);
    bn_finish  <<<1, 320, 0, stream>>>(bn_part, bn_stats);
    theta_kernel<<<NPAD2/4, 256, 0, stream>>>(H, gam, bet, Wt, bt, bn_stats, Hn32, Xn32, Xa, Xb);
    gproj      <<<N_NODES/16, 256, 0, stream>>>(Hn32, Wo, bo, G);
    cos_topk   <<<157*4, 256, 0, stream>>>(Xa, Xb, pidx);
    refine     <<<N_NODES, 64, 0, stream>>>(Xn32, pidx, topA, topI, dinvp);
    outk       <<<N_NODES, 256, 0, stream>>>(G, topA, topI, dinvp, out);
    hipMemsetAsync(Aout, 0, (size_t)N_NODES*N_NODES*sizeof(float), stream);
    scatter    <<<(N_NODES*TOPK + 255)/256, 256, 0, stream>>>(topA, topI, Aout);
}

// Round 4
// 951.772 us; speedup vs baseline: 1.7308x; 1.1495x over previous
//
#include <hip/hip_runtime.h>
#include <hip/hip_bf16.h>
#include <math.h>

#define N_NODES 10000
#define NPAD2   10240     // padded row count for the cos GEMM
#define IN_DIM  144
#define TD      256
#define OD      700
#define TOPK    5
#define GK      160       // padded K for gproj (144 -> 160)
#define GLD     168       // padded LDS row stride (shorts) for gproj tiles

typedef __attribute__((ext_vector_type(8))) short short8v;
typedef __attribute__((ext_vector_type(4))) float f32x4;

__device__ inline unsigned short f32_to_bf16_rne(float f){
    unsigned int u = __float_as_uint(f);
    unsigned int r = u + 0x7fffu + ((u >> 16) & 1u);
    return (unsigned short)(r >> 16);
}

// ---------------- kernel 1: BN partial sums (f64, deterministic) ----------------
__global__ void bn_partial(const float* __restrict__ H, double* __restrict__ part){
    int c = threadIdx.x;
    int b = blockIdx.x;
    if (c >= IN_DIM) return;
    int r0 = b * 250;
    double s = 0.0, q = 0.0;
    for (int r = r0; r < r0 + 250; ++r){
        double v = (double)H[r*IN_DIM + c];
        s += v; q += v*v;
    }
    part[b*288 + c]       = s;
    part[b*288 + 144 + c] = q;
}

__global__ void bn_finish(const double* __restrict__ part, double* __restrict__ stats){
    int c = threadIdx.x;
    if (c >= 288) return;
    double s = 0.0;
    for (int b = 0; b < 40; ++b) s += part[b*288 + c];
    stats[c] = s;
}

// ---------------- kernel 2: BN + theta projection + row normalize ----------------
// Outputs: Xn32 (f32 Xn, for exact refine), Xh (bf16 hi of Xn, cos GEMM operand),
//          Hn16 (bf16 Hn padded [10048][160], gproj operand)
__global__ __launch_bounds__(256) void theta_kernel(
    const float* __restrict__ H, const float* __restrict__ gam, const float* __restrict__ bet,
    const float* __restrict__ Wt, const float* __restrict__ bt, const double* __restrict__ stats,
    float* __restrict__ Xn32, unsigned short* __restrict__ Xh, unsigned short* __restrict__ Hn16)
{
    __shared__ double hn[4][IN_DIM];
    __shared__ double red[4][4];
    __shared__ double invs[4];
    int tid = threadIdx.x;
    int r0 = blockIdx.x * 4;

    if (tid < GK){
        int c = tid;
        bool real = (c < IN_DIM);
        double mean = 0.0, scale = 0.0, bb = 0.0;
        if (real){
            mean  = stats[c] * (1.0/10000.0);
            double var = stats[144+c] * (1.0/10000.0) - mean*mean;
            scale = (1.0/sqrt(var + 1e-5)) * (double)gam[c];
            bb    = (double)bet[c];
        }
        for (int r = 0; r < 4; ++r){
            int row = r0 + r;
            float vf = 0.0f;
            if (real && row < N_NODES)
                vf = (float)(((double)H[row*IN_DIM + c] - mean)*scale + bb);
            if (row < 10048) Hn16[(size_t)row*GK + c] = f32_to_bf16_rne(vf);
            if (real) hn[r][c] = (double)vf;   // f32-rounded value, widened
        }
    }
    __syncthreads();

    int j = tid; // 0..255 == THETA_DIM
    double a0,a1,a2,a3;
    a0=a1=a2=a3=(double)bt[j];
    for (int k = 0; k < IN_DIM; ++k){
        double w = (double)Wt[k*TD + j];
        a0 += hn[0][k]*w; a1 += hn[1][k]*w; a2 += hn[2][k]*w; a3 += hn[3][k]*w;
    }
    float hx0=(float)a0, hx1=(float)a1, hx2=(float)a2, hx3=(float)a3;
    double n0=(double)hx0*(double)hx0, n1=(double)hx1*(double)hx1,
           n2=(double)hx2*(double)hx2, n3=(double)hx3*(double)hx3;
    #pragma unroll
    for (int off=32; off>0; off>>=1){
        n0 += __shfl_down(n0, off);
        n1 += __shfl_down(n1, off);
        n2 += __shfl_down(n2, off);
        n3 += __shfl_down(n3, off);
    }
    int lane = tid & 63, wave = tid >> 6;
    if (lane == 0){ red[0][wave]=n0; red[1][wave]=n1; red[2][wave]=n2; red[3][wave]=n3; }
    __syncthreads();
    if (tid < 4){
        double s = red[tid][0]+red[tid][1]+red[tid][2]+red[tid][3];
        invs[tid] = 1.0 / fmax(sqrt(s), 1e-12);
    }
    __syncthreads();

    float hx[4] = {hx0,hx1,hx2,hx3};
    #pragma unroll
    for (int r = 0; r < 4; ++r){
        int row = r0 + r;
        float xn = 0.0f;
        if (row < N_NODES) xn = (float)((double)hx[r]*invs[r]);
        Xn32[(size_t)row*TD + j] = xn;
        Xh  [(size_t)row*TD + j] = f32_to_bf16_rne(xn);
    }
}

// ---------------- kernel 2b: Wo -> bf16 transposed+padded [704][160] ----------------
__global__ __launch_bounds__(256) void wconv(const float* __restrict__ Wo,
                                             unsigned short* __restrict__ WoT16)
{
    int j = blockIdx.x;        // 0..703
    int k = threadIdx.x;       // 0..255
    if (k >= GK) return;
    float v = (j < OD && k < IN_DIM) ? Wo[k*OD + j] : 0.0f;
    WoT16[(size_t)j*GK + k] = f32_to_bf16_rne(v);
}

// ---------------- kernel 3: G = Hn @ W_out + b_out  (bf16 MFMA) ----------------
__global__ __launch_bounds__(256,2) void gproj(const unsigned short* __restrict__ Hn16,
    const unsigned short* __restrict__ WoT16, const float* __restrict__ bo,
    float* __restrict__ G)
{
    __shared__ short Al[64*GLD];        // 21504 B
    __shared__ short Wl[2][64*GLD];     // 2 x 21504 B
    int tid = threadIdx.x;
    int w = tid >> 6, lane = tid & 63;
    int l15 = lane & 15, l4 = lane >> 4;
    int i0 = blockIdx.x * 64;

    int sr = tid >> 2, sc = tid & 3;
    // stage A-tile (Hn rows i0..i0+63, full K)
    #pragma unroll
    for (int p = 0; p < 5; ++p){
        int cb = sc + (p<<2);
        *(short8v*)(&Al[sr*GLD + cb*8]) =
            *(const short8v*)(&Hn16[(size_t)(i0+sr)*GK + cb*8]);
    }
    // stage W tile 0
    #pragma unroll
    for (int p = 0; p < 5; ++p){
        int cb = sc + (p<<2);
        *(short8v*)(&Wl[0][sr*GLD + cb*8]) =
            *(const short8v*)(&WoT16[(size_t)sr*GK + cb*8]);
    }
    __syncthreads();

    for (int jt = 0; jt < 11; ++jt){
        int cur = jt & 1;
        bool pf = (jt < 10);
        short8v g[5];
        if (pf){
            #pragma unroll
            for (int p = 0; p < 5; ++p){
                int cb = sc + (p<<2);
                g[p] = *(const short8v*)(&WoT16[(size_t)((jt+1)*64 + sr)*GK + cb*8]);
            }
        }
        f32x4 acc[4];
        #pragma unroll
        for (int n=0;n<4;++n) acc[n] = (f32x4){0.f,0.f,0.f,0.f};
        #pragma unroll
        for (int ks = 0; ks < 5; ++ks){
            short8v af = *(const short8v*)(&Al[(w*16 + l15)*GLD + ks*32 + l4*8]);
            #pragma unroll
            for (int n=0;n<4;++n){
                short8v bf = *(const short8v*)(&Wl[cur][(n*16 + l15)*GLD + ks*32 + l4*8]);
                acc[n] = __builtin_amdgcn_mfma_f32_16x16x32_bf16(af, bf, acc[n], 0, 0, 0);
            }
        }
        // store C: row=i (A-op), col=j (B-op)
        #pragma unroll
        for (int n=0;n<4;++n){
            int jcol = jt*64 + n*16 + l15;
            if (jcol < OD){
                float b = bo[jcol];
                #pragma unroll
                for (int q=0;q<4;++q){
                    int irow = i0 + w*16 + l4*4 + q;
                    if (irow < N_NODES)
                        G[(size_t)irow*OD + jcol] = acc[n][q] + b;
                }
            }
        }
        if (pf){
            #pragma unroll
            for (int p = 0; p < 5; ++p){
                int cb = sc + (p<<2);
                *(short8v*)(&Wl[cur^1][sr*GLD + cb*8]) = g[p];
            }
        }
        __syncthreads();
    }
}

// ---------------- kernel 4: MFMA cos GEMM (bf16 hi, K=256) + per-row top-k ----------------
#define CHUNK 2560
#define NJT   40

__global__ __launch_bounds__(256,2) void cos_topk(const unsigned short* __restrict__ Xh,
                                                  int* __restrict__ pidx)
{
    __shared__ short Bl[2][16384];      // 2 x 64 rows x 256 shorts (XOR-swizzled) = 64 KB

    int bid   = blockIdx.x;
    int i0    = (bid >> 2) * 64;
    int chunk = bid & 3;
    int jbeg  = chunk * CHUNK;

    int tid  = threadIdx.x;
    int w    = tid >> 6, lane = tid & 63;
    int l15  = lane & 15, l4 = lane >> 4;

    // i-fragments in registers: rows i0 + n*16 + l15, full K=256
    short8v bfr[4][8];
    #pragma unroll
    for (int n=0;n<4;++n){
        const unsigned short* src = &Xh[(size_t)(i0 + n*16 + l15)*TD + l4*8];
        #pragma unroll
        for (int ks=0;ks<8;++ks)
            bfr[n][ks] = *(const short8v*)(src + ks*32);
    }

    // stage j-tile 0 (swizzled: col-block cb of row r stored at cb ^ (r&7))
    #pragma unroll
    for (int p=0;p<8;++p){
        int idx = (p<<8) + tid;
        int r = idx >> 5, cb = idx & 31;
        short8v v = *(const short8v*)(&Xh[(size_t)(jbeg + r)*TD + (cb<<3)]);
        *(short8v*)(&Bl[0][r*256 + ((cb ^ (r&7))<<3)]) = v;
    }

    float tv[4][5];
    int   tix[4][5];
    #pragma unroll
    for (int n=0;n<4;++n){
        #pragma unroll
        for (int s=0;s<5;++s){ tv[n][s] = -2.0f; tix[n][s] = 0x7fffffff; }
    }
    __syncthreads();

    int rl  = w*16 + l15;        // j-local row this lane reads for the A-op frag
    int swz = (l15 & 7);

    for (int jt = 0; jt < NJT; ++jt){
        int cur = jt & 1;
        bool pf = (jt + 1 < NJT);

        // prefetch next tile into regs (in flight across the MFMA phase)
        short8v g[8];
        if (pf){
            int jn = jbeg + (jt+1)*64;
            #pragma unroll
            for (int p=0;p<8;++p){
                int idx = (p<<8) + tid;
                int r = idx >> 5, cb = idx & 31;
                g[p] = *(const short8v*)(&Xh[(size_t)(jn + r)*TD + (cb<<3)]);
            }
        }

        // compute: 8 k-steps, 4 accumulators (i-quadrants)
        f32x4 acc[4];
        #pragma unroll
        for (int n=0;n<4;++n) acc[n] = (f32x4){0.f,0.f,0.f,0.f};
        #pragma unroll
        for (int ks=0;ks<8;++ks){
            short8v af = *(const short8v*)(&Bl[cur][rl*256 + ((((ks<<2)|l4) ^ swz)<<3)]);
            #pragma unroll
            for (int n=0;n<4;++n)
                acc[n] = __builtin_amdgcn_mfma_f32_16x16x32_bf16(af, bfr[n][ks], acc[n], 0, 0, 0);
        }

        // fold into per-lane top-5 (j ascending -> stable ties)
        int jb = jbeg + jt*64 + w*16 + l4*4;
        #pragma unroll
        for (int n=0;n<4;++n){
            f32x4 a = acc[n];
            float m4 = fmaxf(fmaxf(a[0],a[1]), fmaxf(a[2],a[3]));
            if (m4 >= tv[n][4]){
                #pragma unroll
                for (int q=0;q<4;++q){
                    int j = jb + q;
                    float v = a[q];
                    if (v > tv[n][4] || (v == tv[n][4] && j < tix[n][4])){
                        tv[n][4] = v; tix[n][4] = j;
                        #pragma unroll
                        for (int s=4;s>0;--s){
                            bool sw = (tv[n][s] > tv[n][s-1]) ||
                                      (tv[n][s]==tv[n][s-1] && tix[n][s] < tix[n][s-1]);
                            float fv = tv[n][s]; int fi = tix[n][s];
                            if (sw){
                                tv[n][s]=tv[n][s-1]; tix[n][s]=tix[n][s-1];
                                tv[n][s-1]=fv;       tix[n][s-1]=fi;
                            }
                        }
                    }
                }
            }
        }

        // write prefetched tile into the other buffer, one barrier per tile
        if (pf){
            #pragma unroll
            for (int p=0;p<8;++p){
                int idx = (p<<8) + tid;
                int r = idx >> 5, cb = idx & 31;
                *(short8v*)(&Bl[cur^1][r*256 + ((cb ^ (r&7))<<3)]) = g[p];
            }
        }
        __syncthreads();
    }

    // merge: 16 lists (4 waves x 4 lane-groups) x top5 -> per-row top-16 for this chunk
    float* mv = (float*)&Bl[0][0];            // [64][80] 20480 B
    int*   mi = (int*)&Bl[0][0] + 5120;       // [64][80] 20480 B
    #pragma unroll
    for (int n=0;n<4;++n){
        int ilocal = n*16 + l15;
        int list   = w*4 + l4;
        int base   = ilocal*80 + list*5;
        #pragma unroll
        for (int s=0;s<5;++s){ mv[base+s] = tv[n][s]; mi[base+s] = tix[n][s]; }
    }
    __syncthreads();
    if (tid < 64){
        int gi = i0 + tid;
        if (gi < N_NODES){
            float bv[16]; int bi[16];
            #pragma unroll
            for (int s=0;s<16;++s){ bv[s]=-3.0f; bi[s]=0x7fffffff; }
            int rb = tid*80;
            for (int c2=0;c2<80;++c2){
                float v = mv[rb+c2]; int ix = mi[rb+c2];
                if (v > bv[15] || (v==bv[15] && ix < bi[15])){
                    bv[15]=v; bi[15]=ix;
                    #pragma unroll
                    for (int s=15;s>0;--s){
                        bool sw = (bv[s] > bv[s-1]) || (bv[s]==bv[s-1] && bi[s]<bi[s-1]);
                        float fv=bv[s]; int fi=bi[s];
                        if (sw){ bv[s]=bv[s-1]; bi[s]=bi[s-1]; bv[s-1]=fv; bi[s-1]=fi; }
                    }
                }
            }
            #pragma unroll
            for (int s=0;s<16;++s) pidx[(size_t)gi*64 + chunk*16 + s] = bi[s];
        }
    }
}

// ---------------- kernel 5: refinement — exact cos of f32 Xn, f32 A-chain keys ----------------
__global__ __launch_bounds__(64) void refine(const float* __restrict__ Xn32,
    const int* __restrict__ pidx, float* __restrict__ topA, int* __restrict__ topI,
    float* __restrict__ dinv)
{
    __shared__ float xi[TD];
    int row = blockIdx.x;
    int l = threadIdx.x;
    for (int k = l; k < TD; k += 64) xi[k] = Xn32[(size_t)row*TD + k];
    __syncthreads();

    int j  = pidx[(size_t)row*64 + l];
    int jc = j < N_NODES ? j : 0;
    const float* xj = &Xn32[(size_t)jc*TD];
    double s = 0.0;
    for (int k = 0; k < TD; k += 4){
        float4 b = *(const float4*)(&xj[k]);
        s += (double)xi[k+0]*(double)b.x;
        s += (double)xi[k+1]*(double)b.y;
        s += (double)xi[k+2]*(double)b.z;
        s += (double)xi[k+3]*(double)b.w;
    }
    float cos32 = (float)s;
    cos32 = fminf(fmaxf(cos32, -1.0f), 1.0f);
    float sam = acosf(cos32);
    float e   = expf(-0.2f*sam);
    float key = 1.0f/(1.0f + expf(-e));   // sigmoid; > 0.5 so clip(0.1) is a no-op
    if (j >= N_NODES) key = -1.0f;        // padded rows can never be selected

    double dsum = 0.0;
    for (int t = 0; t < TOPK; ++t){
        float v = key; int ix = j;
        #pragma unroll
        for (int off=32; off>0; off>>=1){
            float ov = __shfl_xor(v, off);
            int oix  = __shfl_xor(ix, off);
            if (ov > v || (ov == v && oix < ix)){ v = ov; ix = oix; }
        }
        dsum += (double)v;
        if (l == 0){ topA[row*TOPK + t] = v; topI[row*TOPK + t] = ix; }
        if (j == ix) key = -1.0f;  // remove selected candidate
    }
    if (l == 0) dinv[row] = (float)(1.0/sqrt(dsum));
}

// ---------------- kernel 6: out = lrelu( A_hat(5-sparse) @ G ) ----------------
__global__ __launch_bounds__(256) void outk(const float* __restrict__ G,
    const float* __restrict__ topA, const int* __restrict__ topI,
    const float* __restrict__ dinv, float* __restrict__ out)
{
    __shared__ float w[TOPK];
    __shared__ int   jj[TOPK];
    int row = blockIdx.x, tid = threadIdx.x;
    if (tid < TOPK){
        int j = topI[row*TOPK + tid];
        jj[tid] = j;
        w[tid]  = topA[row*TOPK + tid] * dinv[row] * dinv[j];
    }
    __syncthreads();
    for (int col = tid; col < OD; col += 256){
        float acc = 0.f;
        #pragma unroll
        for (int m=0;m<TOPK;++m) acc = fmaf(w[m], G[(size_t)jj[m]*OD + col], acc);
        out[(size_t)row*OD + col] = acc >= 0.f ? acc : 0.01f*acc;
    }
}

// ---------------- kernel 7: scatter A values (after memset of A region) ----------------
__global__ void scatter(const float* __restrict__ topA, const int* __restrict__ topI,
                        float* __restrict__ Aout)
{
    int t = blockIdx.x*256 + threadIdx.x;
    if (t >= N_NODES*TOPK) return;
    int row = t / TOPK;
    Aout[(size_t)row*N_NODES + topI[t]] = topA[t];
}

extern "C" void kernel_launch(void* const* d_in, const int* in_sizes, int n_in,
                              void* d_out, int out_size, void* d_ws, size_t ws_size,
                              hipStream_t stream)
{
    const float* H   = (const float*)d_in[0];
    const float* gam = (const float*)d_in[1];
    const float* bet = (const float*)d_in[2];
    const float* Wt  = (const float*)d_in[3];
    const float* bt  = (const float*)d_in[4];
    const float* Wo  = (const float*)d_in[5];
    const float* bo  = (const float*)d_in[6];

    float* out  = (float*)d_out;
    float* Aout = out + (size_t)N_NODES*OD;   // + 7,000,000 floats

    // scratch carved out of the A region of d_out (all consumed before the memset)
    float*          Xn32  = Aout;                               // 10240*256 f   = 2,621,440 f
    unsigned short* Xh    = (unsigned short*)(Aout + 2621440);  // 10240*256 us  = 1,310,720 f
    unsigned short* Hn16  = (unsigned short*)(Aout + 3932160);  // 10048*160 us  =   803,840 f
    unsigned short* WoT16 = (unsigned short*)(Aout + 4736000);  // 704*160 us    =    56,320 f
    float*          G     = Aout + 4792320;                     // 10000*700     = 7,000,000 f
    int*            pidx  = (int*)(Aout + 11792320);            // 10000*64      =   640,000 i
    // ends at 12,432,320 floats < 100,000,000

    // small persistent scratch in ws (needed after the A memset)
    double* bn_part  = (double*)d_ws;             // 40*288 f64
    double* bn_stats = bn_part + 40*288;          // 288 f64
    float*  topA  = (float*)(bn_stats + 288);     // 50,000 f32
    int*    topI  = (int*)(topA + 50000);         // 50,000 i32
    float*  dinvp = (float*)(topI + 50000);       // 10,000 f32

    bn_partial  <<<40, 192, 0, stream>>>(H, bn_part);
    bn_finish   <<<1, 320, 0, stream>>>(bn_part, bn_stats);
    theta_kernel<<<NPAD2/4, 256, 0, stream>>>(H, gam, bet, Wt, bt, bn_stats, Xn32, Xh, Hn16);
    wconv       <<<704, 256, 0, stream>>>(Wo, WoT16);
    gproj       <<<157, 256, 0, stream>>>(Hn16, WoT16, bo, G);
    cos_topk    <<<157*4, 256, 0, stream>>>(Xh, pidx);
    refine      <<<N_NODES, 64, 0, stream>>>(Xn32, pidx, topA, topI, dinvp);
    outk        <<<N_NODES, 256, 0, stream>>>(G, topA, topI, dinvp, out);
    hipMemsetAsync(Aout, 0, (size_t)N_NODES*N_NODES*sizeof(float), stream);
    scatter     <<<(N_NODES*TOPK + 255)/256, 256, 0, stream>>>(topA, topI, Aout);
}

// Round 5
// 543.627 us; speedup vs baseline: 3.0302x; 1.7508x over previous
//
#include <hip/hip_runtime.h>
#include <hip/hip_bf16.h>
#include <math.h>

#define N_NODES 10000
#define NPAD2   10240     // padded row count for the cos GEMM
#define IN_DIM  144
#define TD      256
#define OD      700
#define TOPK    5
#define GK      160       // padded K for gproj (144 -> 160)
#define GLD     168       // padded LDS row stride (shorts) for gproj tiles
#define LDT     72        // padded LDS row stride (shorts) for cos tiles

typedef __attribute__((ext_vector_type(8))) short short8v;
typedef __attribute__((ext_vector_type(4))) float f32x4;

__device__ inline unsigned short f32_to_bf16_rne(float f){
    unsigned int u = __float_as_uint(f);
    unsigned int r = u + 0x7fffu + ((u >> 16) & 1u);
    return (unsigned short)(r >> 16);
}

// ---------------- kernel 1: BN partial sums (f64, deterministic) ----------------
__global__ void bn_partial(const float* __restrict__ H, double* __restrict__ part){
    int c = threadIdx.x;
    int b = blockIdx.x;
    if (c >= IN_DIM) return;
    int r0 = b * 250;
    double s = 0.0, q = 0.0;
    for (int r = r0; r < r0 + 250; ++r){
        double v = (double)H[r*IN_DIM + c];
        s += v; q += v*v;
    }
    part[b*288 + c]       = s;
    part[b*288 + 144 + c] = q;
}

__global__ void bn_finish(const double* __restrict__ part, double* __restrict__ stats){
    int c = threadIdx.x;
    if (c >= 288) return;
    double s = 0.0;
    for (int b = 0; b < 40; ++b) s += part[b*288 + c];
    stats[c] = s;
}

// ---------------- kernel 2: BN + theta projection + row normalize ----------------
__global__ __launch_bounds__(256) void theta_kernel(
    const float* __restrict__ H, const float* __restrict__ gam, const float* __restrict__ bet,
    const float* __restrict__ Wt, const float* __restrict__ bt, const double* __restrict__ stats,
    float* __restrict__ Xn32, unsigned short* __restrict__ Xh, unsigned short* __restrict__ Hn16)
{
    __shared__ double hn[4][IN_DIM];
    __shared__ double red[4][4];
    __shared__ double invs[4];
    int tid = threadIdx.x;
    int r0 = blockIdx.x * 4;

    if (tid < GK){
        int c = tid;
        bool real = (c < IN_DIM);
        double mean = 0.0, scale = 0.0, bb = 0.0;
        if (real){
            mean  = stats[c] * (1.0/10000.0);
            double var = stats[144+c] * (1.0/10000.0) - mean*mean;
            scale = (1.0/sqrt(var + 1e-5)) * (double)gam[c];
            bb    = (double)bet[c];
        }
        for (int r = 0; r < 4; ++r){
            int row = r0 + r;
            float vf = 0.0f;
            if (real && row < N_NODES)
                vf = (float)(((double)H[row*IN_DIM + c] - mean)*scale + bb);
            if (row < 10048) Hn16[(size_t)row*GK + c] = f32_to_bf16_rne(vf);
            if (real) hn[r][c] = (double)vf;   // f32-rounded value, widened
        }
    }
    __syncthreads();

    int j = tid; // 0..255 == THETA_DIM
    double a0,a1,a2,a3;
    a0=a1=a2=a3=(double)bt[j];
    for (int k = 0; k < IN_DIM; ++k){
        double w = (double)Wt[k*TD + j];
        a0 += hn[0][k]*w; a1 += hn[1][k]*w; a2 += hn[2][k]*w; a3 += hn[3][k]*w;
    }
    float hx0=(float)a0, hx1=(float)a1, hx2=(float)a2, hx3=(float)a3;
    double n0=(double)hx0*(double)hx0, n1=(double)hx1*(double)hx1,
           n2=(double)hx2*(double)hx2, n3=(double)hx3*(double)hx3;
    #pragma unroll
    for (int off=32; off>0; off>>=1){
        n0 += __shfl_down(n0, off);
        n1 += __shfl_down(n1, off);
        n2 += __shfl_down(n2, off);
        n3 += __shfl_down(n3, off);
    }
    int lane = tid & 63, wave = tid >> 6;
    if (lane == 0){ red[0][wave]=n0; red[1][wave]=n1; red[2][wave]=n2; red[3][wave]=n3; }
    __syncthreads();
    if (tid < 4){
        double s = red[tid][0]+red[tid][1]+red[tid][2]+red[tid][3];
        invs[tid] = 1.0 / fmax(sqrt(s), 1e-12);
    }
    __syncthreads();

    float hx[4] = {hx0,hx1,hx2,hx3};
    #pragma unroll
    for (int r = 0; r < 4; ++r){
        int row = r0 + r;
        float xn = 0.0f;
        if (row < N_NODES) xn = (float)((double)hx[r]*invs[r]);
        Xn32[(size_t)row*TD + j] = xn;
        Xh  [(size_t)row*TD + j] = f32_to_bf16_rne(xn);
    }
}

// ---------------- kernel 2b: Wo -> bf16 transposed+padded [704][160] ----------------
__global__ __launch_bounds__(256) void wconv(const float* __restrict__ Wo,
                                             unsigned short* __restrict__ WoT16)
{
    int j = blockIdx.x;        // 0..703
    int k = threadIdx.x;       // 0..255
    if (k >= GK) return;
    float v = (j < OD && k < IN_DIM) ? Wo[k*OD + j] : 0.0f;
    WoT16[(size_t)j*GK + k] = f32_to_bf16_rne(v);
}

// ---------------- kernel 3: G = Hn @ W_out + b_out  (bf16 MFMA) ----------------
__global__ __launch_bounds__(256,2) void gproj(const unsigned short* __restrict__ Hn16,
    const unsigned short* __restrict__ WoT16, const float* __restrict__ bo,
    float* __restrict__ G)
{
    __shared__ short Al[64*GLD];        // 21504 B
    __shared__ short Wl[2][64*GLD];     // 2 x 21504 B
    int tid = threadIdx.x;
    int w = tid >> 6, lane = tid & 63;
    int l15 = lane & 15, l4 = lane >> 4;
    int i0 = blockIdx.x * 64;

    int sr = tid >> 2, sc = tid & 3;
    #pragma unroll
    for (int p = 0; p < 5; ++p){
        int cb = sc + (p<<2);
        *(short8v*)(&Al[sr*GLD + cb*8]) =
            *(const short8v*)(&Hn16[(size_t)(i0+sr)*GK + cb*8]);
    }
    #pragma unroll
    for (int p = 0; p < 5; ++p){
        int cb = sc + (p<<2);
        *(short8v*)(&Wl[0][sr*GLD + cb*8]) =
            *(const short8v*)(&WoT16[(size_t)sr*GK + cb*8]);
    }
    __syncthreads();

    for (int jt = 0; jt < 11; ++jt){
        int cur = jt & 1;
        bool pf = (jt < 10);
        short8v g[5];
        if (pf){
            #pragma unroll
            for (int p = 0; p < 5; ++p){
                int cb = sc + (p<<2);
                g[p] = *(const short8v*)(&WoT16[(size_t)((jt+1)*64 + sr)*GK + cb*8]);
            }
        }
        f32x4 acc[4];
        #pragma unroll
        for (int n=0;n<4;++n) acc[n] = (f32x4){0.f,0.f,0.f,0.f};
        #pragma unroll
        for (int ks = 0; ks < 5; ++ks){
            short8v af = *(const short8v*)(&Al[(w*16 + l15)*GLD + ks*32 + l4*8]);
            #pragma unroll
            for (int n=0;n<4;++n){
                short8v bf = *(const short8v*)(&Wl[cur][(n*16 + l15)*GLD + ks*32 + l4*8]);
                acc[n] = __builtin_amdgcn_mfma_f32_16x16x32_bf16(af, bf, acc[n], 0, 0, 0);
            }
        }
        #pragma unroll
        for (int n=0;n<4;++n){
            int jcol = jt*64 + n*16 + l15;
            if (jcol < OD){
                float b = bo[jcol];
                #pragma unroll
                for (int q=0;q<4;++q){
                    int irow = i0 + w*16 + l4*4 + q;
                    if (irow < N_NODES)
                        G[(size_t)irow*OD + jcol] = acc[n][q] + b;
                }
            }
        }
        if (pf){
            #pragma unroll
            for (int p = 0; p < 5; ++p){
                int cb = sc + (p<<2);
                *(short8v*)(&Wl[cur^1][sr*GLD + cb*8]) = g[p];
            }
        }
        __syncthreads();
    }
}

// ---------------- kernel 4: cos Gram 128x128 block + one-shot per-window top-5 ----------------
// Per block: full K=256 tile, then packed-key top-5 per row within this 128-j window.
// Packed key: monotone(f32 cos) upper 25 bits | (127 - j_local) -> order = (cos desc, j asc).
__global__ __launch_bounds__(256,3) void cos_blk(const unsigned short* __restrict__ Xh,
                                                 unsigned int* __restrict__ pkey)
{
    __shared__ unsigned int smem[10240];   // 40960 B (tiles / lists union)
    short* Al = (short*)smem;              // [128][72]  i-rows
    short* Bl = ((short*)smem) + 128*LDT;  // [128][72]  j-rows

    int j0 = blockIdx.x * 128;
    int i0 = blockIdx.y * 128;
    int tid = threadIdx.x;
    int w = tid >> 6, lane = tid & 63;
    int l15 = lane & 15, l4 = lane >> 4;

    f32x4 acc[2][8];
    #pragma unroll
    for (int jf=0;jf<2;++jf){
        #pragma unroll
        for (int f=0;f<8;++f) acc[jf][f] = (f32x4){0.f,0.f,0.f,0.f};
    }

    int str = tid >> 3;     // 0..31 (row in group of 32)
    int scb = tid & 7;      // 0..7  (8-short col block)

    for (int kc = 0; kc < TD; kc += 64){
        __syncthreads();
        #pragma unroll
        for (int p=0;p<4;++p){
            int r = p*32 + str;
            *(short8v*)(&Al[r*LDT + scb*8]) =
                *(const short8v*)(&Xh[(size_t)(i0+r)*TD + kc + scb*8]);
            *(short8v*)(&Bl[r*LDT + scb*8]) =
                *(const short8v*)(&Xh[(size_t)(j0+r)*TD + kc + scb*8]);
        }
        __syncthreads();
        #pragma unroll
        for (int ks=0; ks<2; ++ks){
            short8v af0 = *(const short8v*)(&Bl[(w*32 +  0 + l15)*LDT + ks*32 + l4*8]);
            short8v af1 = *(const short8v*)(&Bl[(w*32 + 16 + l15)*LDT + ks*32 + l4*8]);
            #pragma unroll
            for (int f=0; f<8; ++f){
                short8v bf = *(const short8v*)(&Al[(f*16 + l15)*LDT + ks*32 + l4*8]);
                acc[0][f] = __builtin_amdgcn_mfma_f32_16x16x32_bf16(af0, bf, acc[0][f], 0,0,0);
                acc[1][f] = __builtin_amdgcn_mfma_f32_16x16x32_bf16(af1, bf, acc[1][f], 0,0,0);
            }
        }
    }
    __syncthreads();

    // fold: per (lane, f): top-5 of 8 candidates as packed keys -> LDS lists
    unsigned int* lists = smem;            // [128][80]
    #pragma unroll
    for (int f=0; f<8; ++f){
        unsigned int t5[5] = {0u,0u,0u,0u,0u};
        #pragma unroll
        for (int jf=0; jf<2; ++jf){
            #pragma unroll
            for (int q=0; q<4; ++q){
                float v = acc[jf][f][q];
                int jl = w*32 + jf*16 + l4*4 + q;
                unsigned int u = __float_as_uint(v);
                unsigned int key = ((int)u < 0) ? ~u : (u | 0x80000000u);
                unsigned int pk = (key & 0xFFFFFF80u) | (unsigned int)(127 - jl);
                if (pk > t5[4]){
                    t5[4] = pk;
                    #pragma unroll
                    for (int s=4;s>0;--s){
                        if (t5[s] > t5[s-1]){ unsigned int tp=t5[s]; t5[s]=t5[s-1]; t5[s-1]=tp; }
                    }
                }
            }
        }
        int row  = f*16 + l15;
        int base = row*80 + (w*4 + l4)*5;
        #pragma unroll
        for (int s=0;s<5;++s) lists[base+s] = t5[s];
    }
    __syncthreads();

    if (tid < 128){
        unsigned int b5[5] = {0u,0u,0u,0u,0u};
        int rb = tid*80;
        for (int c=0;c<80;++c){
            unsigned int pk = lists[rb + c];
            if (pk > b5[4]){
                b5[4] = pk;
                #pragma unroll
                for (int s=4;s>0;--s){
                    if (b5[s] > b5[s-1]){ unsigned int tp=b5[s]; b5[s]=b5[s-1]; b5[s-1]=tp; }
                }
            }
        }
        size_t gb = (size_t)(i0 + tid)*400 + (size_t)blockIdx.x*5;
        #pragma unroll
        for (int s=0;s<5;++s) pkey[gb + s] = b5[s];
    }
}

// ---------------- kernel 4b: merge 80 windows x top-5 -> global top-16 (+dup fill) ----------------
__global__ __launch_bounds__(64) void merge_topk(const unsigned int* __restrict__ pkey,
                                                 int* __restrict__ pidx)
{
    __shared__ unsigned int sk[400];
    int row = blockIdx.x, l = threadIdx.x;
    const unsigned int* pr = &pkey[(size_t)row*400];
    for (int t = l; t < 400; t += 64) sk[t] = pr[t];
    __syncthreads();
    int first = 0;
    for (int s=0; s<16; ++s){
        unsigned int bk = 0u; int bj = 0x7fffffff; int bslot = -1;
        for (int t = l; t < 400; t += 64){
            unsigned int k = sk[t];
            int gj = (t/5)*128 + 127 - (int)(k & 127u);
            if (k > bk || (k == bk && gj < bj)){ bk = k; bj = gj; bslot = t; }
        }
        unsigned int v = bk; int ix = bj;
        #pragma unroll
        for (int off=32; off>0; off>>=1){
            unsigned int ov = (unsigned int)__shfl_xor((int)v, off);
            int oj = __shfl_xor(ix, off);
            if (ov > v || (ov == v && oj < ix)){ v = ov; ix = oj; }
        }
        if (s == 0) first = ix;
        if (l == 0) pidx[(size_t)row*64 + s] = ix;
        if (bk == v && bj == ix && bslot >= 0) sk[bslot] = 0u;  // unique winner clears its slot
        __syncthreads();
    }
    if (l >= 16) pidx[(size_t)row*64 + l] = first;   // dup fill (dedup'd in refine)
}

// ---------------- kernel 5: refinement — exact cos of f32 Xn, f32 A-chain keys ----------------
__global__ __launch_bounds__(64) void refine(const float* __restrict__ Xn32,
    const int* __restrict__ pidx, float* __restrict__ topA, int* __restrict__ topI,
    float* __restrict__ dinv)
{
    __shared__ float xi[TD];
    int row = blockIdx.x;
    int l = threadIdx.x;
    for (int k = l; k < TD; k += 64) xi[k] = Xn32[(size_t)row*TD + k];
    __syncthreads();

    int j  = pidx[(size_t)row*64 + l];
    int jc = j < N_NODES ? j : 0;
    const float* xj = &Xn32[(size_t)jc*TD];
    double s = 0.0;
    for (int k = 0; k < TD; k += 4){
        float4 b = *(const float4*)(&xj[k]);
        s += (double)xi[k+0]*(double)b.x;
        s += (double)xi[k+1]*(double)b.y;
        s += (double)xi[k+2]*(double)b.z;
        s += (double)xi[k+3]*(double)b.w;
    }
    float cos32 = (float)s;
    cos32 = fminf(fmaxf(cos32, -1.0f), 1.0f);
    float sam = acosf(cos32);
    float e   = expf(-0.2f*sam);
    float key = 1.0f/(1.0f + expf(-e));   // sigmoid; > 0.5 so clip(0.1) is a no-op
    if (j >= N_NODES) key = -1.0f;        // padded rows can never be selected

    double dsum = 0.0;
    for (int t = 0; t < TOPK; ++t){
        float v = key; int ix = j;
        #pragma unroll
        for (int off=32; off>0; off>>=1){
            float ov = __shfl_xor(v, off);
            int oix  = __shfl_xor(ix, off);
            if (ov > v || (ov == v && oix < ix)){ v = ov; ix = oix; }
        }
        dsum += (double)v;
        if (l == 0){ topA[row*TOPK + t] = v; topI[row*TOPK + t] = ix; }
        if (j == ix) key = -1.0f;  // remove selected candidate (also removes dups)
    }
    if (l == 0) dinv[row] = (float)(1.0/sqrt(dsum));
}

// ---------------- kernel 6: out = lrelu( A_hat(5-sparse) @ G ) ----------------
__global__ __launch_bounds__(256) void outk(const float* __restrict__ G,
    const float* __restrict__ topA, const int* __restrict__ topI,
    const float* __restrict__ dinv, float* __restrict__ out)
{
    __shared__ float w[TOPK];
    __shared__ int   jj[TOPK];
    int row = blockIdx.x, tid = threadIdx.x;
    if (tid < TOPK){
        int j = topI[row*TOPK + tid];
        jj[tid] = j;
        w[tid]  = topA[row*TOPK + tid] * dinv[row] * dinv[j];
    }
    __syncthreads();
    for (int col = tid; col < OD; col += 256){
        float acc = 0.f;
        #pragma unroll
        for (int m=0;m<TOPK;++m) acc = fmaf(w[m], G[(size_t)jj[m]*OD + col], acc);
        out[(size_t)row*OD + col] = acc >= 0.f ? acc : 0.01f*acc;
    }
}

// ---------------- kernel 7: scatter A values (after memset of A region) ----------------
__global__ void scatter(const float* __restrict__ topA, const int* __restrict__ topI,
                        float* __restrict__ Aout)
{
    int t = blockIdx.x*256 + threadIdx.x;
    if (t >= N_NODES*TOPK) return;
    int row = t / TOPK;
    Aout[(size_t)row*N_NODES + topI[t]] = topA[t];
}

extern "C" void kernel_launch(void* const* d_in, const int* in_sizes, int n_in,
                              void* d_out, int out_size, void* d_ws, size_t ws_size,
                              hipStream_t stream)
{
    const float* H   = (const float*)d_in[0];
    const float* gam = (const float*)d_in[1];
    const float* bet = (const float*)d_in[2];
    const float* Wt  = (const float*)d_in[3];
    const float* bt  = (const float*)d_in[4];
    const float* Wo  = (const float*)d_in[5];
    const float* bo  = (const float*)d_in[6];

    float* out  = (float*)d_out;
    float* Aout = out + (size_t)N_NODES*OD;   // + 7,000,000 floats

    // scratch carved out of the A region of d_out (all consumed before the memset)
    float*          Xn32  = Aout;                               // 10240*256 f   = 2,621,440 f
    unsigned short* Xh    = (unsigned short*)(Aout + 2621440);  // 10240*256 us  = 1,310,720 f
    unsigned short* Hn16  = (unsigned short*)(Aout + 3932160);  // 10048*160 us  =   803,840 f
    unsigned short* WoT16 = (unsigned short*)(Aout + 4736000);  // 704*160 us    =    56,320 f
    float*          G     = Aout + 4792320;                     // 10000*700     = 7,000,000 f
    unsigned int*   pkey  = (unsigned int*)(Aout + 11792320);   // 10240*400     = 4,096,000 u
    int*            pidx  = (int*)(Aout + 15888320);            // 10000*64      =   640,000 i
    // ends at 16,528,320 floats < 100,000,000

    // small persistent scratch in ws (needed after the A memset)
    double* bn_part  = (double*)d_ws;             // 40*288 f64
    double* bn_stats = bn_part + 40*288;          // 288 f64
    float*  topA  = (float*)(bn_stats + 288);     // 50,000 f32
    int*    topI  = (int*)(topA + 50000);         // 50,000 i32
    float*  dinvp = (float*)(topI + 50000);       // 10,000 f32

    bn_partial  <<<40, 192, 0, stream>>>(H, bn_part);
    bn_finish   <<<1, 320, 0, stream>>>(bn_part, bn_stats);
    theta_kernel<<<NPAD2/4, 256, 0, stream>>>(H, gam, bet, Wt, bt, bn_stats, Xn32, Xh, Hn16);
    wconv       <<<704, 256, 0, stream>>>(Wo, WoT16);
    gproj       <<<157, 256, 0, stream>>>(Hn16, WoT16, bo, G);
    cos_blk     <<<dim3(80,80), 256, 0, stream>>>(Xh, pkey);
    merge_topk  <<<N_NODES, 64, 0, stream>>>(pkey, pidx);
    refine      <<<N_NODES, 64, 0, stream>>>(Xn32, pidx, topA, topI, dinvp);
    outk        <<<N_NODES, 256, 0, stream>>>(G, topA, topI, dinvp, out);
    hipMemsetAsync(Aout, 0, (size_t)N_NODES*N_NODES*sizeof(float), stream);
    scatter     <<<(N_NODES*TOPK + 255)/256, 256, 0, stream>>>(topA, topI, Aout);
}

// Round 6
// 542.121 us; speedup vs baseline: 3.0386x; 1.0028x over previous
//
#include <hip/hip_runtime.h>
#include <hip/hip_bf16.h>
#include <math.h>

#define N_NODES 10000
#define NPAD2   10240     // padded row count for the cos GEMM
#define IN_DIM  144
#define TD      256
#define OD      700
#define TOPK    5
#define GK      160       // padded K for gproj (144 -> 160)
#define GLD     168       // padded LDS row stride (shorts) for gproj tiles
#define LDT     72        // padded LDS row stride (shorts) for cos tiles

typedef __attribute__((ext_vector_type(8))) short short8v;
typedef __attribute__((ext_vector_type(4))) float f32x4;

__device__ inline unsigned short f32_to_bf16_rne(float f){
    unsigned int u = __float_as_uint(f);
    unsigned int r = u + 0x7fffu + ((u >> 16) & 1u);
    return (unsigned short)(r >> 16);
}

// ---------------- kernel 1: BN partial sums (f64, deterministic) ----------------
__global__ void bn_partial(const float* __restrict__ H, double* __restrict__ part){
    int c = threadIdx.x;
    int b = blockIdx.x;
    if (c >= IN_DIM) return;
    int r0 = b * 250;
    double s = 0.0, q = 0.0;
    for (int r = r0; r < r0 + 250; ++r){
        double v = (double)H[r*IN_DIM + c];
        s += v; q += v*v;
    }
    part[b*288 + c]       = s;
    part[b*288 + 144 + c] = q;
}

__global__ void bn_finish(const double* __restrict__ part, double* __restrict__ stats){
    int c = threadIdx.x;
    if (c >= 288) return;
    double s = 0.0;
    for (int b = 0; b < 40; ++b) s += part[b*288 + c];
    stats[c] = s;
}

// ---------------- kernel 2: BN + theta projection + row normalize ----------------
__global__ __launch_bounds__(256) void theta_kernel(
    const float* __restrict__ H, const float* __restrict__ gam, const float* __restrict__ bet,
    const float* __restrict__ Wt, const float* __restrict__ bt, const double* __restrict__ stats,
    float* __restrict__ Xn32, unsigned short* __restrict__ Xh, unsigned short* __restrict__ Hn16)
{
    __shared__ double hn[4][IN_DIM];
    __shared__ double red[4][4];
    __shared__ double invs[4];
    int tid = threadIdx.x;
    int r0 = blockIdx.x * 4;

    if (tid < GK){
        int c = tid;
        bool real = (c < IN_DIM);
        double mean = 0.0, scale = 0.0, bb = 0.0;
        if (real){
            mean  = stats[c] * (1.0/10000.0);
            double var = stats[144+c] * (1.0/10000.0) - mean*mean;
            scale = (1.0/sqrt(var + 1e-5)) * (double)gam[c];
            bb    = (double)bet[c];
        }
        for (int r = 0; r < 4; ++r){
            int row = r0 + r;
            float vf = 0.0f;
            if (real && row < N_NODES)
                vf = (float)(((double)H[row*IN_DIM + c] - mean)*scale + bb);
            if (row < 10048) Hn16[(size_t)row*GK + c] = f32_to_bf16_rne(vf);
            if (real) hn[r][c] = (double)vf;   // f32-rounded value, widened
        }
    }
    __syncthreads();

    int j = tid; // 0..255 == THETA_DIM
    double a0,a1,a2,a3;
    a0=a1=a2=a3=(double)bt[j];
    for (int k = 0; k < IN_DIM; ++k){
        double w = (double)Wt[k*TD + j];
        a0 += hn[0][k]*w; a1 += hn[1][k]*w; a2 += hn[2][k]*w; a3 += hn[3][k]*w;
    }
    float hx0=(float)a0, hx1=(float)a1, hx2=(float)a2, hx3=(float)a3;
    double n0=(double)hx0*(double)hx0, n1=(double)hx1*(double)hx1,
           n2=(double)hx2*(double)hx2, n3=(double)hx3*(double)hx3;
    #pragma unroll
    for (int off=32; off>0; off>>=1){
        n0 += __shfl_down(n0, off);
        n1 += __shfl_down(n1, off);
        n2 += __shfl_down(n2, off);
        n3 += __shfl_down(n3, off);
    }
    int lane = tid & 63, wave = tid >> 6;
    if (lane == 0){ red[0][wave]=n0; red[1][wave]=n1; red[2][wave]=n2; red[3][wave]=n3; }
    __syncthreads();
    if (tid < 4){
        double s = red[tid][0]+red[tid][1]+red[tid][2]+red[tid][3];
        invs[tid] = 1.0 / fmax(sqrt(s), 1e-12);
    }
    __syncthreads();

    float hx[4] = {hx0,hx1,hx2,hx3};
    #pragma unroll
    for (int r = 0; r < 4; ++r){
        int row = r0 + r;
        float xn = 0.0f;
        if (row < N_NODES) xn = (float)((double)hx[r]*invs[r]);
        Xn32[(size_t)row*TD + j] = xn;
        Xh  [(size_t)row*TD + j] = f32_to_bf16_rne(xn);
    }
}

// ---------------- kernel 2b: Wo -> bf16 transposed+padded [704][160] ----------------
__global__ __launch_bounds__(256) void wconv(const float* __restrict__ Wo,
                                             unsigned short* __restrict__ WoT16)
{
    int j = blockIdx.x;        // 0..703
    int k = threadIdx.x;       // 0..255
    if (k >= GK) return;
    float v = (j < OD && k < IN_DIM) ? Wo[k*OD + j] : 0.0f;
    WoT16[(size_t)j*GK + k] = f32_to_bf16_rne(v);
}

// ---------------- kernel 3: G = Hn @ W_out + b_out  (bf16 MFMA) ----------------
__global__ __launch_bounds__(256,2) void gproj(const unsigned short* __restrict__ Hn16,
    const unsigned short* __restrict__ WoT16, const float* __restrict__ bo,
    float* __restrict__ G)
{
    __shared__ short Al[64*GLD];        // 21504 B
    __shared__ short Wl[2][64*GLD];     // 2 x 21504 B
    int tid = threadIdx.x;
    int w = tid >> 6, lane = tid & 63;
    int l15 = lane & 15, l4 = lane >> 4;
    int i0 = blockIdx.x * 64;

    int sr = tid >> 2, sc = tid & 3;
    #pragma unroll
    for (int p = 0; p < 5; ++p){
        int cb = sc + (p<<2);
        *(short8v*)(&Al[sr*GLD + cb*8]) =
            *(const short8v*)(&Hn16[(size_t)(i0+sr)*GK + cb*8]);
    }
    #pragma unroll
    for (int p = 0; p < 5; ++p){
        int cb = sc + (p<<2);
        *(short8v*)(&Wl[0][sr*GLD + cb*8]) =
            *(const short8v*)(&WoT16[(size_t)sr*GK + cb*8]);
    }
    __syncthreads();

    for (int jt = 0; jt < 11; ++jt){
        int cur = jt & 1;
        bool pf = (jt < 10);
        short8v g[5];
        if (pf){
            #pragma unroll
            for (int p = 0; p < 5; ++p){
                int cb = sc + (p<<2);
                g[p] = *(const short8v*)(&WoT16[(size_t)((jt+1)*64 + sr)*GK + cb*8]);
            }
        }
        f32x4 acc[4];
        #pragma unroll
        for (int n=0;n<4;++n) acc[n] = (f32x4){0.f,0.f,0.f,0.f};
        #pragma unroll
        for (int ks = 0; ks < 5; ++ks){
            short8v af = *(const short8v*)(&Al[(w*16 + l15)*GLD + ks*32 + l4*8]);
            #pragma unroll
            for (int n=0;n<4;++n){
                short8v bf = *(const short8v*)(&Wl[cur][(n*16 + l15)*GLD + ks*32 + l4*8]);
                acc[n] = __builtin_amdgcn_mfma_f32_16x16x32_bf16(af, bf, acc[n], 0, 0, 0);
            }
        }
        #pragma unroll
        for (int n=0;n<4;++n){
            int jcol = jt*64 + n*16 + l15;
            if (jcol < OD){
                float b = bo[jcol];
                #pragma unroll
                for (int q=0;q<4;++q){
                    int irow = i0 + w*16 + l4*4 + q;
                    if (irow < N_NODES)
                        G[(size_t)irow*OD + jcol] = acc[n][q] + b;
                }
            }
        }
        if (pf){
            #pragma unroll
            for (int p = 0; p < 5; ++p){
                int cb = sc + (p<<2);
                *(short8v*)(&Wl[cur^1][sr*GLD + cb*8]) = g[p];
            }
        }
        __syncthreads();
    }
}

// ---------------- kernel 4: cos Gram 128x128 block + one-shot per-window top-5 ----------------
__global__ __launch_bounds__(256,3) void cos_blk(const unsigned short* __restrict__ Xh,
                                                 unsigned int* __restrict__ pkey)
{
    __shared__ unsigned int smem[10240];   // 40960 B (tiles / lists union)
    short* Al = (short*)smem;              // [128][72]  i-rows
    short* Bl = ((short*)smem) + 128*LDT;  // [128][72]  j-rows

    int j0 = blockIdx.x * 128;
    int i0 = blockIdx.y * 128;
    int tid = threadIdx.x;
    int w = tid >> 6, lane = tid & 63;
    int l15 = lane & 15, l4 = lane >> 4;

    f32x4 acc[2][8];
    #pragma unroll
    for (int jf=0;jf<2;++jf){
        #pragma unroll
        for (int f=0;f<8;++f) acc[jf][f] = (f32x4){0.f,0.f,0.f,0.f};
    }

    int str = tid >> 3;     // 0..31 (row in group of 32)
    int scb = tid & 7;      // 0..7  (8-short col block)

    for (int kc = 0; kc < TD; kc += 64){
        __syncthreads();
        #pragma unroll
        for (int p=0;p<4;++p){
            int r = p*32 + str;
            *(short8v*)(&Al[r*LDT + scb*8]) =
                *(const short8v*)(&Xh[(size_t)(i0+r)*TD + kc + scb*8]);
            *(short8v*)(&Bl[r*LDT + scb*8]) =
                *(const short8v*)(&Xh[(size_t)(j0+r)*TD + kc + scb*8]);
        }
        __syncthreads();
        #pragma unroll
        for (int ks=0; ks<2; ++ks){
            short8v af0 = *(const short8v*)(&Bl[(w*32 +  0 + l15)*LDT + ks*32 + l4*8]);
            short8v af1 = *(const short8v*)(&Bl[(w*32 + 16 + l15)*LDT + ks*32 + l4*8]);
            #pragma unroll
            for (int f=0; f<8; ++f){
                short8v bf = *(const short8v*)(&Al[(f*16 + l15)*LDT + ks*32 + l4*8]);
                acc[0][f] = __builtin_amdgcn_mfma_f32_16x16x32_bf16(af0, bf, acc[0][f], 0,0,0);
                acc[1][f] = __builtin_amdgcn_mfma_f32_16x16x32_bf16(af1, bf, acc[1][f], 0,0,0);
            }
        }
    }
    __syncthreads();

    // fold: per (lane, f): top-5 of 8 candidates as packed keys -> LDS lists
    unsigned int* lists = smem;            // [128][80]
    #pragma unroll
    for (int f=0; f<8; ++f){
        unsigned int t5[5] = {0u,0u,0u,0u,0u};
        #pragma unroll
        for (int jf=0; jf<2; ++jf){
            #pragma unroll
            for (int q=0; q<4; ++q){
                float v = acc[jf][f][q];
                int jl = w*32 + jf*16 + l4*4 + q;
                unsigned int u = __float_as_uint(v);
                unsigned int key = ((int)u < 0) ? ~u : (u | 0x80000000u);
                unsigned int pk = (key & 0xFFFFFF80u) | (unsigned int)(127 - jl);
                if (pk > t5[4]){
                    t5[4] = pk;
                    #pragma unroll
                    for (int s=4;s>0;--s){
                        if (t5[s] > t5[s-1]){ unsigned int tp=t5[s]; t5[s]=t5[s-1]; t5[s-1]=tp; }
                    }
                }
            }
        }
        int row  = f*16 + l15;
        int base = row*80 + (w*4 + l4)*5;
        #pragma unroll
        for (int s=0;s<5;++s) lists[base+s] = t5[s];
    }
    __syncthreads();

    if (tid < 128){
        unsigned int b5[5] = {0u,0u,0u,0u,0u};
        int rb = tid*80;
        for (int c=0;c<80;++c){
            unsigned int pk = lists[rb + c];
            if (pk > b5[4]){
                b5[4] = pk;
                #pragma unroll
                for (int s=4;s>0;--s){
                    if (b5[s] > b5[s-1]){ unsigned int tp=b5[s]; b5[s]=b5[s-1]; b5[s-1]=tp; }
                }
            }
        }
        size_t gb = (size_t)(i0 + tid)*400 + (size_t)blockIdx.x*5;
        #pragma unroll
        for (int s=0;s<5;++s) pkey[gb + s] = b5[s];
    }
}

// ---------------- kernel 4b: merge 80 windows x top-5 -> global top-16 (+dup fill) ----------------
__global__ __launch_bounds__(64) void merge_topk(const unsigned int* __restrict__ pkey,
                                                 int* __restrict__ pidx)
{
    __shared__ unsigned int sk[400];
    int row = blockIdx.x, l = threadIdx.x;
    const unsigned int* pr = &pkey[(size_t)row*400];
    for (int t = l; t < 400; t += 64) sk[t] = pr[t];
    __syncthreads();
    int first = 0;
    for (int s=0; s<16; ++s){
        unsigned int bk = 0u; int bj = 0x7fffffff; int bslot = -1;
        for (int t = l; t < 400; t += 64){
            unsigned int k = sk[t];
            int gj = (t/5)*128 + 127 - (int)(k & 127u);
            if (k > bk || (k == bk && gj < bj)){ bk = k; bj = gj; bslot = t; }
        }
        unsigned int v = bk; int ix = bj;
        #pragma unroll
        for (int off=32; off>0; off>>=1){
            unsigned int ov = (unsigned int)__shfl_xor((int)v, off);
            int oj = __shfl_xor(ix, off);
            if (ov > v || (ov == v && oj < ix)){ v = ov; ix = oj; }
        }
        if (s == 0) first = ix;
        if (l == 0) pidx[(size_t)row*64 + s] = ix;
        if (bk == v && bj == ix && bslot >= 0) sk[bslot] = 0u;  // unique winner clears its slot
        __syncthreads();
    }
    if (l >= 16) pidx[(size_t)row*64 + l] = first;   // dup fill (dedup'd in refine)
}

// ---------------- kernel 5: refinement — exact cos of f32 Xn, f32 A-chain keys ----------------
__global__ __launch_bounds__(64) void refine(const float* __restrict__ Xn32,
    const int* __restrict__ pidx, float* __restrict__ topA, int* __restrict__ topI,
    float* __restrict__ dinv)
{
    __shared__ float xi[TD];
    int row = blockIdx.x;
    int l = threadIdx.x;
    for (int k = l; k < TD; k += 64) xi[k] = Xn32[(size_t)row*TD + k];
    __syncthreads();

    int j  = pidx[(size_t)row*64 + l];
    int jc = j < N_NODES ? j : 0;
    const float* xj = &Xn32[(size_t)jc*TD];
    double s = 0.0;
    for (int k = 0; k < TD; k += 4){
        float4 b = *(const float4*)(&xj[k]);
        s += (double)xi[k+0]*(double)b.x;
        s += (double)xi[k+1]*(double)b.y;
        s += (double)xi[k+2]*(double)b.z;
        s += (double)xi[k+3]*(double)b.w;
    }
    float cos32 = (float)s;
    cos32 = fminf(fmaxf(cos32, -1.0f), 1.0f);
    float sam = acosf(cos32);
    float e   = expf(-0.2f*sam);
    float key = 1.0f/(1.0f + expf(-e));   // sigmoid; > 0.5 so clip(0.1) is a no-op
    if (j >= N_NODES) key = -1.0f;        // padded rows can never be selected

    double dsum = 0.0;
    for (int t = 0; t < TOPK; ++t){
        float v = key; int ix = j;
        #pragma unroll
        for (int off=32; off>0; off>>=1){
            float ov = __shfl_xor(v, off);
            int oix  = __shfl_xor(ix, off);
            if (ov > v || (ov == v && oix < ix)){ v = ov; ix = oix; }
        }
        dsum += (double)v;
        if (l == 0){ topA[row*TOPK + t] = v; topI[row*TOPK + t] = ix; }
        if (j == ix) key = -1.0f;  // remove selected candidate (also removes dups)
    }
    if (l == 0) dinv[row] = (float)(1.0/sqrt(dsum));
}

// ---------------- kernel 6: out = lrelu( A_hat(5-sparse) @ G ) ----------------
__global__ __launch_bounds__(256) void outk(const float* __restrict__ G,
    const float* __restrict__ topA, const int* __restrict__ topI,
    const float* __restrict__ dinv, float* __restrict__ out)
{
    __shared__ float w[TOPK];
    __shared__ int   jj[TOPK];
    int row = blockIdx.x, tid = threadIdx.x;
    if (tid < TOPK){
        int j = topI[row*TOPK + tid];
        jj[tid] = j;
        w[tid]  = topA[row*TOPK + tid] * dinv[row] * dinv[j];
    }
    __syncthreads();
    for (int col = tid; col < OD; col += 256){
        float acc = 0.f;
        #pragma unroll
        for (int m=0;m<TOPK;++m) acc = fmaf(w[m], G[(size_t)jj[m]*OD + col], acc);
        out[(size_t)row*OD + col] = acc >= 0.f ? acc : 0.01f*acc;
    }
}

// ---------------- kernel 7: zero the A row + scatter its 5 values (one block/row) ----------------
// Replaces hipMemsetAsync (runtime fill showed 4x HBM write amplification) + scatter.
__global__ __launch_bounds__(256) void zero_scatter(const float* __restrict__ topA,
    const int* __restrict__ topI, float* __restrict__ Aout)
{
    int row = blockIdx.x;
    float4* rowp = (float4*)(Aout + (size_t)row*N_NODES);
    const float4 z = {0.f,0.f,0.f,0.f};
    int tid = threadIdx.x;
    #pragma unroll
    for (int p = 0; p < 10; ++p){
        int c = p*256 + tid;
        if (c < 2500) rowp[c] = z;
    }
    __syncthreads();
    if (tid < TOPK)
        Aout[(size_t)row*N_NODES + topI[row*TOPK + tid]] = topA[row*TOPK + tid];
}

extern "C" void kernel_launch(void* const* d_in, const int* in_sizes, int n_in,
                              void* d_out, int out_size, void* d_ws, size_t ws_size,
                              hipStream_t stream)
{
    const float* H   = (const float*)d_in[0];
    const float* gam = (const float*)d_in[1];
    const float* bet = (const float*)d_in[2];
    const float* Wt  = (const float*)d_in[3];
    const float* bt  = (const float*)d_in[4];
    const float* Wo  = (const float*)d_in[5];
    const float* bo  = (const float*)d_in[6];

    float* out  = (float*)d_out;
    float* Aout = out + (size_t)N_NODES*OD;   // + 7,000,000 floats

    // scratch carved out of the A region of d_out (all consumed before zero_scatter)
    float*          Xn32  = Aout;                               // 10240*256 f   = 2,621,440 f
    unsigned short* Xh    = (unsigned short*)(Aout + 2621440);  // 10240*256 us  = 1,310,720 f
    unsigned short* Hn16  = (unsigned short*)(Aout + 3932160);  // 10048*160 us  =   803,840 f
    unsigned short* WoT16 = (unsigned short*)(Aout + 4736000);  // 704*160 us    =    56,320 f
    float*          G     = Aout + 4792320;                     // 10000*700     = 7,000,000 f
    unsigned int*   pkey  = (unsigned int*)(Aout + 11792320);   // 10240*400     = 4,096,000 u
    int*            pidx  = (int*)(Aout + 15888320);            // 10000*64      =   640,000 i
    // ends at 16,528,320 floats < 100,000,000

    // small persistent scratch in ws (needed after the A overwrite)
    double* bn_part  = (double*)d_ws;             // 40*288 f64
    double* bn_stats = bn_part + 40*288;          // 288 f64
    float*  topA  = (float*)(bn_stats + 288);     // 50,000 f32
    int*    topI  = (int*)(topA + 50000);         // 50,000 i32
    float*  dinvp = (float*)(topI + 50000);       // 10,000 f32

    bn_partial  <<<40, 192, 0, stream>>>(H, bn_part);
    bn_finish   <<<1, 320, 0, stream>>>(bn_part, bn_stats);
    theta_kernel<<<NPAD2/4, 256, 0, stream>>>(H, gam, bet, Wt, bt, bn_stats, Xn32, Xh, Hn16);
    wconv       <<<704, 256, 0, stream>>>(Wo, WoT16);
    gproj       <<<157, 256, 0, stream>>>(Hn16, WoT16, bo, G);
    cos_blk     <<<dim3(80,80), 256, 0, stream>>>(Xh, pkey);
    merge_topk  <<<N_NODES, 64, 0, stream>>>(pkey, pidx);
    refine      <<<N_NODES, 64, 0, stream>>>(Xn32, pidx, topA, topI, dinvp);
    outk        <<<N_NODES, 256, 0, stream>>>(G, topA, topI, dinvp, out);
    zero_scatter<<<N_NODES, 256, 0, stream>>>(topA, topI, Aout);
}

// Round 8
// 419.674 us; speedup vs baseline: 3.9252x; 1.2918x over previous
//
#include <hip/hip_runtime.h>
#include <hip/hip_bf16.h>
#include <math.h>

#define N_NODES 10000
#define NPAD2   10240     // padded row count for the cos GEMM
#define IN_DIM  144
#define TD      256
#define OD      700
#define TOPK    5
#define GK      160       // padded K for gproj (144 -> 160)
#define GLD     168       // padded LDS row stride (shorts) for gproj tiles
#define LDT     72        // padded LDS row stride (shorts) for cos tiles

typedef __attribute__((ext_vector_type(8))) short short8v;
typedef __attribute__((ext_vector_type(4))) float f32x4;

__device__ inline unsigned short f32_to_bf16_rne(float f){
    unsigned int u = __float_as_uint(f);
    unsigned int r = u + 0x7fffu + ((u >> 16) & 1u);
    return (unsigned short)(r >> 16);
}

// ---------------- kernel 1: BN partial sums (f64, deterministic) ----------------
__global__ void bn_partial(const float* __restrict__ H, double* __restrict__ part){
    int c = threadIdx.x;
    int b = blockIdx.x;
    if (c >= IN_DIM) return;
    int r0 = b * 80;
    double s = 0.0, q = 0.0;
    #pragma unroll 4
    for (int r = r0; r < r0 + 80; ++r){
        double v = (double)H[r*IN_DIM + c];
        s += v; q += v*v;
    }
    part[b*288 + c]       = s;
    part[b*288 + 144 + c] = q;
}

__global__ void bn_finish(const double* __restrict__ part, double* __restrict__ stats){
    int c = threadIdx.x;
    if (c >= 288) return;
    double s = 0.0;
    for (int b = 0; b < 125; ++b) s += part[b*288 + c];
    stats[c] = s;
}

// ---------------- kernel 2: BN + theta projection + row normalize ----------------
__global__ __launch_bounds__(256) void theta_kernel(
    const float* __restrict__ H, const float* __restrict__ gam, const float* __restrict__ bet,
    const float* __restrict__ Wt, const float* __restrict__ bt, const double* __restrict__ stats,
    float* __restrict__ Xn32, unsigned short* __restrict__ Xh, unsigned short* __restrict__ Hn16)
{
    __shared__ double hn[4][IN_DIM];
    __shared__ double red[4][4];
    __shared__ double invs[4];
    int tid = threadIdx.x;
    int r0 = blockIdx.x * 4;

    if (tid < GK){
        int c = tid;
        bool real = (c < IN_DIM);
        double mean = 0.0, scale = 0.0, bb = 0.0;
        if (real){
            mean  = stats[c] * (1.0/10000.0);
            double var = stats[144+c] * (1.0/10000.0) - mean*mean;
            scale = (1.0/sqrt(var + 1e-5)) * (double)gam[c];
            bb    = (double)bet[c];
        }
        for (int r = 0; r < 4; ++r){
            int row = r0 + r;
            float vf = 0.0f;
            if (real && row < N_NODES)
                vf = (float)(((double)H[row*IN_DIM + c] - mean)*scale + bb);
            if (row < 10048) Hn16[(size_t)row*GK + c] = f32_to_bf16_rne(vf);
            if (real) hn[r][c] = (double)vf;   // f32-rounded value, widened
        }
    }
    __syncthreads();

    int j = tid; // 0..255 == THETA_DIM
    double a0,a1,a2,a3;
    a0=a1=a2=a3=(double)bt[j];
    for (int k = 0; k < IN_DIM; ++k){
        double w = (double)Wt[k*TD + j];
        a0 += hn[0][k]*w; a1 += hn[1][k]*w; a2 += hn[2][k]*w; a3 += hn[3][k]*w;
    }
    float hx0=(float)a0, hx1=(float)a1, hx2=(float)a2, hx3=(float)a3;
    double n0=(double)hx0*(double)hx0, n1=(double)hx1*(double)hx1,
           n2=(double)hx2*(double)hx2, n3=(double)hx3*(double)hx3;
    #pragma unroll
    for (int off=32; off>0; off>>=1){
        n0 += __shfl_down(n0, off);
        n1 += __shfl_down(n1, off);
        n2 += __shfl_down(n2, off);
        n3 += __shfl_down(n3, off);
    }
    int lane = tid & 63, wave = tid >> 6;
    if (lane == 0){ red[0][wave]=n0; red[1][wave]=n1; red[2][wave]=n2; red[3][wave]=n3; }
    __syncthreads();
    if (tid < 4){
        double s = red[tid][0]+red[tid][1]+red[tid][2]+red[tid][3];
        invs[tid] = 1.0 / fmax(sqrt(s), 1e-12);
    }
    __syncthreads();

    float hx[4] = {hx0,hx1,hx2,hx3};
    #pragma unroll
    for (int r = 0; r < 4; ++r){
        int row = r0 + r;
        float xn = 0.0f;
        if (row < N_NODES) xn = (float)((double)hx[r]*invs[r]);
        Xn32[(size_t)row*TD + j] = xn;
        Xh  [(size_t)row*TD + j] = f32_to_bf16_rne(xn);
    }
}

// ---------------- kernel 2b: Wo -> bf16 transposed+padded [704][160] ----------------
__global__ __launch_bounds__(256) void wconv(const float* __restrict__ Wo,
                                             unsigned short* __restrict__ WoT16)
{
    int j = blockIdx.x;        // 0..703
    int k = threadIdx.x;       // 0..255
    if (k >= GK) return;
    float v = (j < OD && k < IN_DIM) ? Wo[k*OD + j] : 0.0f;
    WoT16[(size_t)j*GK + k] = f32_to_bf16_rne(v);
}

// ---------------- kernel 3: G = Hn @ W_out + b_out  (bf16 MFMA) ----------------
__global__ __launch_bounds__(256,2) void gproj(const unsigned short* __restrict__ Hn16,
    const unsigned short* __restrict__ WoT16, const float* __restrict__ bo,
    float* __restrict__ G)
{
    __shared__ short Al[64*GLD];        // 21504 B
    __shared__ short Wl[2][64*GLD];     // 2 x 21504 B
    int tid = threadIdx.x;
    int w = tid >> 6, lane = tid & 63;
    int l15 = lane & 15, l4 = lane >> 4;
    int i0 = blockIdx.x * 64;

    int sr = tid >> 2, sc = tid & 3;
    #pragma unroll
    for (int p = 0; p < 5; ++p){
        int cb = sc + (p<<2);
        *(short8v*)(&Al[sr*GLD + cb*8]) =
            *(const short8v*)(&Hn16[(size_t)(i0+sr)*GK + cb*8]);
    }
    #pragma unroll
    for (int p = 0; p < 5; ++p){
        int cb = sc + (p<<2);
        *(short8v*)(&Wl[0][sr*GLD + cb*8]) =
            *(const short8v*)(&WoT16[(size_t)sr*GK + cb*8]);
    }
    __syncthreads();

    for (int jt = 0; jt < 11; ++jt){
        int cur = jt & 1;
        bool pf = (jt < 10);
        short8v g[5];
        if (pf){
            #pragma unroll
            for (int p = 0; p < 5; ++p){
                int cb = sc + (p<<2);
                g[p] = *(const short8v*)(&WoT16[(size_t)((jt+1)*64 + sr)*GK + cb*8]);
            }
        }
        f32x4 acc[4];
        #pragma unroll
        for (int n=0;n<4;++n) acc[n] = (f32x4){0.f,0.f,0.f,0.f};
        #pragma unroll
        for (int ks = 0; ks < 5; ++ks){
            short8v af = *(const short8v*)(&Al[(w*16 + l15)*GLD + ks*32 + l4*8]);
            #pragma unroll
            for (int n=0;n<4;++n){
                short8v bf = *(const short8v*)(&Wl[cur][(n*16 + l15)*GLD + ks*32 + l4*8]);
                acc[n] = __builtin_amdgcn_mfma_f32_16x16x32_bf16(af, bf, acc[n], 0, 0, 0);
            }
        }
        #pragma unroll
        for (int n=0;n<4;++n){
            int jcol = jt*64 + n*16 + l15;
            if (jcol < OD){
                float b = bo[jcol];
                #pragma unroll
                for (int q=0;q<4;++q){
                    int irow = i0 + w*16 + l4*4 + q;
                    if (irow < N_NODES)
                        G[(size_t)irow*OD + jcol] = acc[n][q] + b;
                }
            }
        }
        if (pf){
            #pragma unroll
            for (int p = 0; p < 5; ++p){
                int cb = sc + (p<<2);
                *(short8v*)(&Wl[cur^1][sr*GLD + cb*8]) = g[p];
            }
        }
        __syncthreads();
    }
}

// ---------------- kernel 4: symmetric cos Gram, upper-triangle tiles only ----------------
// Each block (bi<=bj) computes the 128x128 tile once and folds BOTH directions:
//   direct:     i-rows get j-candidates -> pkey window bj
//   transposed: j-rows get i-candidates -> pkey window bi (skipped when bi==bj)
// Packed key: monotone(f32 cos) upper 25 bits | (127 - local_idx) -> (cos desc, idx asc).
__global__ __launch_bounds__(256,3) void cos_blk(const unsigned short* __restrict__ Xh,
                                                 unsigned int* __restrict__ pkey)
{
    __shared__ unsigned int smem[10240];   // 40960 B (tiles / lists union)
    short* Al = (short*)smem;              // [128][72]  i-rows
    short* Bl = ((short*)smem) + 128*LDT;  // [128][72]  j-rows

    // decode upper-triangle pair (bi <= bj) from linear block id
    int t = blockIdx.x;
    int bi = 0, rem = t;
    while (rem >= 80 - bi){ rem -= 80 - bi; ++bi; }
    int bj = bi + rem;
    int i0 = bi * 128;
    int j0 = bj * 128;

    int tid = threadIdx.x;
    int w = tid >> 6, lane = tid & 63;
    int l15 = lane & 15, l4 = lane >> 4;

    f32x4 acc[2][8];
    #pragma unroll
    for (int jf=0;jf<2;++jf){
        #pragma unroll
        for (int f=0;f<8;++f) acc[jf][f] = (f32x4){0.f,0.f,0.f,0.f};
    }

    int str = tid >> 3;     // 0..31 (row in group of 32)
    int scb = tid & 7;      // 0..7  (8-short col block)

    for (int kc = 0; kc < TD; kc += 64){
        __syncthreads();
        #pragma unroll
        for (int p=0;p<4;++p){
            int r = p*32 + str;
            *(short8v*)(&Al[r*LDT + scb*8]) =
                *(const short8v*)(&Xh[(size_t)(i0+r)*TD + kc + scb*8]);
            *(short8v*)(&Bl[r*LDT + scb*8]) =
                *(const short8v*)(&Xh[(size_t)(j0+r)*TD + kc + scb*8]);
        }
        __syncthreads();
        #pragma unroll
        for (int ks=0; ks<2; ++ks){
            short8v af0 = *(const short8v*)(&Bl[(w*32 +  0 + l15)*LDT + ks*32 + l4*8]);
            short8v af1 = *(const short8v*)(&Bl[(w*32 + 16 + l15)*LDT + ks*32 + l4*8]);
            #pragma unroll
            for (int f=0; f<8; ++f){
                short8v bf = *(const short8v*)(&Al[(f*16 + l15)*LDT + ks*32 + l4*8]);
                acc[0][f] = __builtin_amdgcn_mfma_f32_16x16x32_bf16(af0, bf, acc[0][f], 0,0,0);
                acc[1][f] = __builtin_amdgcn_mfma_f32_16x16x32_bf16(af1, bf, acc[1][f], 0,0,0);
            }
        }
    }
    __syncthreads();

    unsigned int* lists = smem;            // [128][80]

    // ---- direct fold: per i-column, top-5 over the 8 j-values this lane holds ----
    #pragma unroll
    for (int f=0; f<8; ++f){
        unsigned int t5[5] = {0u,0u,0u,0u,0u};
        #pragma unroll
        for (int jf=0; jf<2; ++jf){
            #pragma unroll
            for (int q=0; q<4; ++q){
                float v = acc[jf][f][q];
                int jl = w*32 + jf*16 + l4*4 + q;
                unsigned int u = __float_as_uint(v);
                unsigned int key = ((int)u < 0) ? ~u : (u | 0x80000000u);
                unsigned int pk = (key & 0xFFFFFF80u) | (unsigned int)(127 - jl);
                if (pk > t5[4]){
                    t5[4] = pk;
                    #pragma unroll
                    for (int s=4;s>0;--s){
                        if (t5[s] > t5[s-1]){ unsigned int tp=t5[s]; t5[s]=t5[s-1]; t5[s-1]=tp; }
                    }
                }
            }
        }
        int row  = f*16 + l15;
        int base = row*80 + (w*4 + l4)*5;
        #pragma unroll
        for (int s=0;s<5;++s) lists[base+s] = t5[s];
    }
    __syncthreads();

    if (tid < 128){
        unsigned int b5[5] = {0u,0u,0u,0u,0u};
        int rb = tid*80;
        for (int c=0;c<80;++c){
            unsigned int pk = lists[rb + c];
            if (pk > b5[4]){
                b5[4] = pk;
                #pragma unroll
                for (int s=4;s>0;--s){
                    if (b5[s] > b5[s-1]){ unsigned int tp=b5[s]; b5[s]=b5[s-1]; b5[s-1]=tp; }
                }
            }
        }
        size_t gb = (size_t)(i0 + tid)*400 + (size_t)bj*5;
        #pragma unroll
        for (int s=0;s<5;++s) pkey[gb + s] = b5[s];
    }

    if (bi == bj) return;   // diagonal: direct fold already covered all pairs

    __syncthreads();

    // ---- transposed fold: per j-row, top-5 over the 8 i-values this lane holds ----
    #pragma unroll
    for (int jf=0; jf<2; ++jf){
        #pragma unroll
        for (int q=0; q<4; ++q){
            unsigned int t5[5] = {0u,0u,0u,0u,0u};
            #pragma unroll
            for (int f=0; f<8; ++f){
                float v = acc[jf][f][q];
                int il = f*16 + l15;
                unsigned int u = __float_as_uint(v);
                unsigned int key = ((int)u < 0) ? ~u : (u | 0x80000000u);
                unsigned int pk = (key & 0xFFFFFF80u) | (unsigned int)(127 - il);
                if (pk > t5[4]){
                    t5[4] = pk;
                    #pragma unroll
                    for (int s=4;s>0;--s){
                        if (t5[s] > t5[s-1]){ unsigned int tp=t5[s]; t5[s]=t5[s-1]; t5[s-1]=tp; }
                    }
                }
            }
            int jl   = w*32 + jf*16 + l4*4 + q;
            int base = jl*80 + l15*5;
            #pragma unroll
            for (int s=0;s<5;++s) lists[base+s] = t5[s];
        }
    }
    __syncthreads();

    if (tid < 128){
        unsigned int b5[5] = {0u,0u,0u,0u,0u};
        int rb = tid*80;
        for (int c=0;c<80;++c){
            unsigned int pk = lists[rb + c];
            if (pk > b5[4]){
                b5[4] = pk;
                #pragma unroll
                for (int s=4;s>0;--s){
                    if (b5[s] > b5[s-1]){ unsigned int tp=b5[s]; b5[s]=b5[s-1]; b5[s-1]=tp; }
                }
            }
        }
        size_t gb = (size_t)(j0 + tid)*400 + (size_t)bi*5;
        #pragma unroll
        for (int s=0;s<5;++s) pkey[gb + s] = b5[s];
    }
}

// ---------------- kernel 4b: merge 80 windows x top-5 -> global top-16 ----------------
__global__ __launch_bounds__(64) void merge_topk(const unsigned int* __restrict__ pkey,
                                                 int* __restrict__ pidx)
{
    __shared__ unsigned int sk[400];
    int row = blockIdx.x, l = threadIdx.x;
    const unsigned int* pr = &pkey[(size_t)row*400];
    for (int t = l; t < 400; t += 64) sk[t] = pr[t];
    __syncthreads();
    for (int s=0; s<16; ++s){
        unsigned int bk = 0u; int bj = 0x7fffffff; int bslot = -1;
        for (int t = l; t < 400; t += 64){
            unsigned int k = sk[t];
            int gj = (t/5)*128 + 127 - (int)(k & 127u);
            if (k > bk || (k == bk && gj < bj)){ bk = k; bj = gj; bslot = t; }
        }
        unsigned int v = bk; int ix = bj;
        #pragma unroll
        for (int off=32; off>0; off>>=1){
            unsigned int ov = (unsigned int)__shfl_xor((int)v, off);
            int oj = __shfl_xor(ix, off);
            if (ov > v || (ov == v && oj < ix)){ v = ov; ix = oj; }
        }
        if (l == 0) pidx[(size_t)row*16 + s] = ix;
        if (bk == v && bj == ix && bslot >= 0) sk[bslot] = 0u;  // unique winner clears its slot
        __syncthreads();
    }
}

// ---------------- kernel 5: refinement — exact cos of f32 Xn, f32 A-chain keys ----------------
// 4 rows/block, 16 lanes per row (16 distinct candidates each).
__global__ __launch_bounds__(64) void refine(const float* __restrict__ Xn32,
    const int* __restrict__ pidx, float* __restrict__ topA, int* __restrict__ topI,
    float* __restrict__ dinv)
{
    __shared__ float xi[4][TD];
    int l = threadIdx.x;
    int grp = l >> 4, slot = l & 15;
    int row0 = blockIdx.x * 4;
    for (int t = l; t < 4*TD; t += 64)
        xi[t>>8][t&255] = Xn32[(size_t)(row0 + (t>>8))*TD + (t&255)];
    __syncthreads();

    int row = row0 + grp;
    int j  = pidx[(size_t)row*16 + slot];
    int jc = j < N_NODES ? j : 0;
    const float* xj = &Xn32[(size_t)jc*TD];
    const float* xr = xi[grp];
    double s = 0.0;
    for (int k = 0; k < TD; k += 4){
        float4 b = *(const float4*)(&xj[k]);
        s += (double)xr[k+0]*(double)b.x;
        s += (double)xr[k+1]*(double)b.y;
        s += (double)xr[k+2]*(double)b.z;
        s += (double)xr[k+3]*(double)b.w;
    }
    float cos32 = (float)s;
    cos32 = fminf(fmaxf(cos32, -1.0f), 1.0f);
    float sam = acosf(cos32);
    float e   = expf(-0.2f*sam);
    float key = 1.0f/(1.0f + expf(-e));   // sigmoid; > 0.5 so clip(0.1) is a no-op
    if (j >= N_NODES) key = -1.0f;        // padded rows can never be selected

    double dsum = 0.0;
    for (int t = 0; t < TOPK; ++t){
        float v = key; int ix = j;
        #pragma unroll
        for (int off=8; off>0; off>>=1){   // reduce within the 16-lane group
            float ov = __shfl_xor(v, off);
            int oix  = __shfl_xor(ix, off);
            if (ov > v || (ov == v && oix < ix)){ v = ov; ix = oix; }
        }
        dsum += (double)v;
        if (slot == 0){ topA[row*TOPK + t] = v; topI[row*TOPK + t] = ix; }
        if (j == ix) key = -1.0f;  // remove selected candidate
    }
    if (slot == 0) dinv[row] = (float)(1.0/sqrt(dsum));
}

// ---------------- kernel 6: out = lrelu( A_hat(5-sparse) @ G ) ----------------
// MUST run fully before zero_scatter: G lives inside the A region.
__global__ __launch_bounds__(256) void outk(const float* __restrict__ G,
    const float* __restrict__ topA, const int* __restrict__ topI,
    const float* __restrict__ dinv, float* __restrict__ out)
{
    __shared__ float w[TOPK];
    __shared__ int   jj[TOPK];
    int row = blockIdx.x, tid = threadIdx.x;
    if (tid < TOPK){
        int j = topI[row*TOPK + tid];
        jj[tid] = j;
        w[tid]  = topA[row*TOPK + tid] * dinv[row] * dinv[j];
    }
    __syncthreads();
    for (int col = tid; col < OD; col += 256){
        float acc = 0.f;
        #pragma unroll
        for (int m=0;m<TOPK;++m) acc = fmaf(w[m], G[(size_t)jj[m]*OD + col], acc);
        out[(size_t)row*OD + col] = acc >= 0.f ? acc : 0.01f*acc;
    }
}

// ---------------- kernel 7: zero the A row + scatter its 5 values (one block/row) ----------------
__global__ __launch_bounds__(256) void zero_scatter(const float* __restrict__ topA,
    const int* __restrict__ topI, float* __restrict__ Aout)
{
    int row = blockIdx.x;
    float4* rowp = (float4*)(Aout + (size_t)row*N_NODES);
    const float4 z = {0.f,0.f,0.f,0.f};
    int tid = threadIdx.x;
    #pragma unroll
    for (int p = 0; p < 10; ++p){
        int c = p*256 + tid;
        if (c < 2500) rowp[c] = z;
    }
    __syncthreads();
    if (tid < TOPK)
        Aout[(size_t)row*N_NODES + topI[row*TOPK + tid]] = topA[row*TOPK + tid];
}

extern "C" void kernel_launch(void* const* d_in, const int* in_sizes, int n_in,
                              void* d_out, int out_size, void* d_ws, size_t ws_size,
                              hipStream_t stream)
{
    const float* H   = (const float*)d_in[0];
    const float* gam = (const float*)d_in[1];
    const float* bet = (const float*)d_in[2];
    const float* Wt  = (const float*)d_in[3];
    const float* bt  = (const float*)d_in[4];
    const float* Wo  = (const float*)d_in[5];
    const float* bo  = (const float*)d_in[6];

    float* out  = (float*)d_out;
    float* Aout = out + (size_t)N_NODES*OD;   // + 7,000,000 floats

    // scratch carved out of the A region of d_out (all consumed before zero_scatter)
    float*          Xn32  = Aout;                               // 10240*256 f   = 2,621,440 f
    unsigned short* Xh    = (unsigned short*)(Aout + 2621440);  // 10240*256 us  = 1,310,720 f
    unsigned short* Hn16  = (unsigned short*)(Aout + 3932160);  // 10048*160 us  =   803,840 f
    unsigned short* WoT16 = (unsigned short*)(Aout + 4736000);  // 704*160 us    =    56,320 f
    float*          G     = Aout + 4792320;                     // 10000*700     = 7,000,000 f
    unsigned int*   pkey  = (unsigned int*)(Aout + 11792320);   // 10240*400     = 4,096,000 u
    int*            pidx  = (int*)(Aout + 15888320);            // 10000*16      =   160,000 i
    double*         bn_part = (double*)(Aout + 16048320);       // 125*288 f64   =    72,000 f
    // ends at ~16.12M floats < 100,000,000

    // small persistent scratch in ws (needed after the A overwrite)
    double* bn_stats = (double*)d_ws;             // 288 f64
    float*  topA  = (float*)(bn_stats + 288);     // 50,000 f32
    int*    topI  = (int*)(topA + 50000);         // 50,000 i32
    float*  dinvp = (float*)(topI + 50000);       // 10,000 f32

    bn_partial  <<<125, 192, 0, stream>>>(H, bn_part);
    bn_finish   <<<1, 320, 0, stream>>>(bn_part, bn_stats);
    theta_kernel<<<NPAD2/4, 256, 0, stream>>>(H, gam, bet, Wt, bt, bn_stats, Xn32, Xh, Hn16);
    wconv       <<<704, 256, 0, stream>>>(Wo, WoT16);
    gproj       <<<157, 256, 0, stream>>>(Hn16, WoT16, bo, G);
    cos_blk     <<<3240, 256, 0, stream>>>(Xh, pkey);
    merge_topk  <<<N_NODES, 64, 0, stream>>>(pkey, pidx);
    refine      <<<2500, 64, 0, stream>>>(Xn32, pidx, topA, topI, dinvp);
    outk        <<<N_NODES, 256, 0, stream>>>(G, topA, topI, dinvp, out);
    zero_scatter<<<N_NODES, 256, 0, stream>>>(topA, topI, Aout);
}

// Round 9
// 399.214 us; speedup vs baseline: 4.1263x; 1.0513x over previous
//
#include <hip/hip_runtime.h>
#include <hip/hip_bf16.h>
#include <math.h>

#define N_NODES 10000
#define NPAD2   10240     // padded row count for the cos GEMM
#define IN_DIM  144
#define TD      256
#define OD      700
#define TOPK    5
#define GK      160       // padded K for gproj (144 -> 160)
#define GLD     168       // padded LDS row stride (shorts) for gproj tiles
#define LDT     72        // padded LDS row stride (shorts) for cos tiles

typedef __attribute__((ext_vector_type(8))) short short8v;
typedef __attribute__((ext_vector_type(4))) float f32x4;

__device__ inline unsigned short f32_to_bf16_rne(float f){
    unsigned int u = __float_as_uint(f);
    unsigned int r = u + 0x7fffu + ((u >> 16) & 1u);
    return (unsigned short)(r >> 16);
}

// ---------------- kernel 1: BN partial sums (f64, deterministic) ----------------
__global__ void bn_partial(const float* __restrict__ H, double* __restrict__ part){
    int c = threadIdx.x;
    int b = blockIdx.x;
    if (c >= IN_DIM) return;
    int r0 = b * 80;
    double s = 0.0, q = 0.0;
    #pragma unroll 4
    for (int r = r0; r < r0 + 80; ++r){
        double v = (double)H[r*IN_DIM + c];
        s += v; q += v*v;
    }
    part[b*288 + c]       = s;
    part[b*288 + 144 + c] = q;
}

__global__ void bn_finish(const double* __restrict__ part, double* __restrict__ stats){
    int c = threadIdx.x;
    if (c >= 288) return;
    double s = 0.0;
    for (int b = 0; b < 125; ++b) s += part[b*288 + c];
    stats[c] = s;
}

// ---------------- kernel 2: BN + theta projection + row normalize (+ fused Wo conv) ----------------
__global__ __launch_bounds__(256) void theta_kernel(
    const float* __restrict__ H, const float* __restrict__ gam, const float* __restrict__ bet,
    const float* __restrict__ Wt, const float* __restrict__ bt, const double* __restrict__ stats,
    const float* __restrict__ Wo, unsigned short* __restrict__ WoT16,
    float* __restrict__ Xn32, unsigned short* __restrict__ Xh, unsigned short* __restrict__ Hn16)
{
    __shared__ double hn[4][IN_DIM];
    __shared__ double red[4][4];
    __shared__ double invs[4];
    int tid = threadIdx.x;
    int r0 = blockIdx.x * 4;

    // fused wconv: blocks 0..703 each convert one Wo row -> WoT16 [704][160] bf16
    if (blockIdx.x < 704 && tid < GK){
        int jj = blockIdx.x;
        float v = (jj < OD && tid < IN_DIM) ? Wo[tid*OD + jj] : 0.0f;
        WoT16[(size_t)jj*GK + tid] = f32_to_bf16_rne(v);
    }

    if (tid < GK){
        int c = tid;
        bool real = (c < IN_DIM);
        double mean = 0.0, scale = 0.0, bb = 0.0;
        if (real){
            mean  = stats[c] * (1.0/10000.0);
            double var = stats[144+c] * (1.0/10000.0) - mean*mean;
            scale = (1.0/sqrt(var + 1e-5)) * (double)gam[c];
            bb    = (double)bet[c];
        }
        for (int r = 0; r < 4; ++r){
            int row = r0 + r;
            float vf = 0.0f;
            if (real && row < N_NODES)
                vf = (float)(((double)H[row*IN_DIM + c] - mean)*scale + bb);
            if (row < 10048) Hn16[(size_t)row*GK + c] = f32_to_bf16_rne(vf);
            if (real) hn[r][c] = (double)vf;   // f32-rounded value, widened
        }
    }
    __syncthreads();

    int j = tid; // 0..255 == THETA_DIM
    double a0,a1,a2,a3;
    a0=a1=a2=a3=(double)bt[j];
    for (int k = 0; k < IN_DIM; ++k){
        double w = (double)Wt[k*TD + j];
        a0 += hn[0][k]*w; a1 += hn[1][k]*w; a2 += hn[2][k]*w; a3 += hn[3][k]*w;
    }
    float hx0=(float)a0, hx1=(float)a1, hx2=(float)a2, hx3=(float)a3;
    double n0=(double)hx0*(double)hx0, n1=(double)hx1*(double)hx1,
           n2=(double)hx2*(double)hx2, n3=(double)hx3*(double)hx3;
    #pragma unroll
    for (int off=32; off>0; off>>=1){
        n0 += __shfl_down(n0, off);
        n1 += __shfl_down(n1, off);
        n2 += __shfl_down(n2, off);
        n3 += __shfl_down(n3, off);
    }
    int lane = tid & 63, wave = tid >> 6;
    if (lane == 0){ red[0][wave]=n0; red[1][wave]=n1; red[2][wave]=n2; red[3][wave]=n3; }
    __syncthreads();
    if (tid < 4){
        double s = red[tid][0]+red[tid][1]+red[tid][2]+red[tid][3];
        invs[tid] = 1.0 / fmax(sqrt(s), 1e-12);
    }
    __syncthreads();

    float hx[4] = {hx0,hx1,hx2,hx3};
    #pragma unroll
    for (int r = 0; r < 4; ++r){
        int row = r0 + r;
        float xn = 0.0f;
        if (row < N_NODES) xn = (float)((double)hx[r]*invs[r]);
        Xn32[(size_t)row*TD + j] = xn;
        Xh  [(size_t)row*TD + j] = f32_to_bf16_rne(xn);
    }
}

// ---------------- kernel 3: G = Hn @ W_out + b_out  (bf16 MFMA) ----------------
__global__ __launch_bounds__(256,2) void gproj(const unsigned short* __restrict__ Hn16,
    const unsigned short* __restrict__ WoT16, const float* __restrict__ bo,
    float* __restrict__ G)
{
    __shared__ short Al[64*GLD];        // 21504 B
    __shared__ short Wl[2][64*GLD];     // 2 x 21504 B
    int tid = threadIdx.x;
    int w = tid >> 6, lane = tid & 63;
    int l15 = lane & 15, l4 = lane >> 4;
    int i0 = blockIdx.x * 64;

    int sr = tid >> 2, sc = tid & 3;
    #pragma unroll
    for (int p = 0; p < 5; ++p){
        int cb = sc + (p<<2);
        *(short8v*)(&Al[sr*GLD + cb*8]) =
            *(const short8v*)(&Hn16[(size_t)(i0+sr)*GK + cb*8]);
    }
    #pragma unroll
    for (int p = 0; p < 5; ++p){
        int cb = sc + (p<<2);
        *(short8v*)(&Wl[0][sr*GLD + cb*8]) =
            *(const short8v*)(&WoT16[(size_t)sr*GK + cb*8]);
    }
    __syncthreads();

    for (int jt = 0; jt < 11; ++jt){
        int cur = jt & 1;
        bool pf = (jt < 10);
        short8v g[5];
        if (pf){
            #pragma unroll
            for (int p = 0; p < 5; ++p){
                int cb = sc + (p<<2);
                g[p] = *(const short8v*)(&WoT16[(size_t)((jt+1)*64 + sr)*GK + cb*8]);
            }
        }
        f32x4 acc[4];
        #pragma unroll
        for (int n=0;n<4;++n) acc[n] = (f32x4){0.f,0.f,0.f,0.f};
        #pragma unroll
        for (int ks = 0; ks < 5; ++ks){
            short8v af = *(const short8v*)(&Al[(w*16 + l15)*GLD + ks*32 + l4*8]);
            #pragma unroll
            for (int n=0;n<4;++n){
                short8v bf = *(const short8v*)(&Wl[cur][(n*16 + l15)*GLD + ks*32 + l4*8]);
                acc[n] = __builtin_amdgcn_mfma_f32_16x16x32_bf16(af, bf, acc[n], 0, 0, 0);
            }
        }
        #pragma unroll
        for (int n=0;n<4;++n){
            int jcol = jt*64 + n*16 + l15;
            if (jcol < OD){
                float b = bo[jcol];
                #pragma unroll
                for (int q=0;q<4;++q){
                    int irow = i0 + w*16 + l4*4 + q;
                    if (irow < N_NODES)
                        G[(size_t)irow*OD + jcol] = acc[n][q] + b;
                }
            }
        }
        if (pf){
            #pragma unroll
            for (int p = 0; p < 5; ++p){
                int cb = sc + (p<<2);
                *(short8v*)(&Wl[cur^1][sr*GLD + cb*8]) = g[p];
            }
        }
        __syncthreads();
    }
}

// ---------------- kernel 4: symmetric cos Gram, upper-triangle tiles only ----------------
__global__ __launch_bounds__(256,3) void cos_blk(const unsigned short* __restrict__ Xh,
                                                 unsigned int* __restrict__ pkey)
{
    __shared__ unsigned int smem[10240];   // 40960 B (tiles / lists union)
    short* Al = (short*)smem;              // [128][72]  i-rows
    short* Bl = ((short*)smem) + 128*LDT;  // [128][72]  j-rows

    // decode upper-triangle pair (bi <= bj) from linear block id
    int t = blockIdx.x;
    int bi = 0, rem = t;
    while (rem >= 80 - bi){ rem -= 80 - bi; ++bi; }
    int bj = bi + rem;
    int i0 = bi * 128;
    int j0 = bj * 128;

    int tid = threadIdx.x;
    int w = tid >> 6, lane = tid & 63;
    int l15 = lane & 15, l4 = lane >> 4;

    f32x4 acc[2][8];
    #pragma unroll
    for (int jf=0;jf<2;++jf){
        #pragma unroll
        for (int f=0;f<8;++f) acc[jf][f] = (f32x4){0.f,0.f,0.f,0.f};
    }

    int str = tid >> 3;     // 0..31 (row in group of 32)
    int scb = tid & 7;      // 0..7  (8-short col block)

    for (int kc = 0; kc < TD; kc += 64){
        __syncthreads();
        #pragma unroll
        for (int p=0;p<4;++p){
            int r = p*32 + str;
            *(short8v*)(&Al[r*LDT + scb*8]) =
                *(const short8v*)(&Xh[(size_t)(i0+r)*TD + kc + scb*8]);
            *(short8v*)(&Bl[r*LDT + scb*8]) =
                *(const short8v*)(&Xh[(size_t)(j0+r)*TD + kc + scb*8]);
        }
        __syncthreads();
        #pragma unroll
        for (int ks=0; ks<2; ++ks){
            short8v af0 = *(const short8v*)(&Bl[(w*32 +  0 + l15)*LDT + ks*32 + l4*8]);
            short8v af1 = *(const short8v*)(&Bl[(w*32 + 16 + l15)*LDT + ks*32 + l4*8]);
            #pragma unroll
            for (int f=0; f<8; ++f){
                short8v bf = *(const short8v*)(&Al[(f*16 + l15)*LDT + ks*32 + l4*8]);
                acc[0][f] = __builtin_amdgcn_mfma_f32_16x16x32_bf16(af0, bf, acc[0][f], 0,0,0);
                acc[1][f] = __builtin_amdgcn_mfma_f32_16x16x32_bf16(af1, bf, acc[1][f], 0,0,0);
            }
        }
    }
    __syncthreads();

    unsigned int* lists = smem;            // [128][80]

    // ---- direct fold: per i-column, top-5 over the 8 j-values this lane holds ----
    #pragma unroll
    for (int f=0; f<8; ++f){
        unsigned int t5[5] = {0u,0u,0u,0u,0u};
        #pragma unroll
        for (int jf=0; jf<2; ++jf){
            #pragma unroll
            for (int q=0; q<4; ++q){
                float v = acc[jf][f][q];
                int jl = w*32 + jf*16 + l4*4 + q;
                unsigned int u = __float_as_uint(v);
                unsigned int key = ((int)u < 0) ? ~u : (u | 0x80000000u);
                unsigned int pk = (key & 0xFFFFFF80u) | (unsigned int)(127 - jl);
                if (pk > t5[4]){
                    t5[4] = pk;
                    #pragma unroll
                    for (int s=4;s>0;--s){
                        if (t5[s] > t5[s-1]){ unsigned int tp=t5[s]; t5[s]=t5[s-1]; t5[s-1]=tp; }
                    }
                }
            }
        }
        int row  = f*16 + l15;
        int base = row*80 + (w*4 + l4)*5;
        #pragma unroll
        for (int s=0;s<5;++s) lists[base+s] = t5[s];
    }
    __syncthreads();

    if (tid < 128){
        unsigned int b5[5] = {0u,0u,0u,0u,0u};
        int rb = tid*80;
        for (int c=0;c<80;++c){
            unsigned int pk = lists[rb + c];
            if (pk > b5[4]){
                b5[4] = pk;
                #pragma unroll
                for (int s=4;s>0;--s){
                    if (b5[s] > b5[s-1]){ unsigned int tp=b5[s]; b5[s]=b5[s-1]; b5[s-1]=tp; }
                }
            }
        }
        size_t gb = (size_t)(i0 + tid)*400 + (size_t)bj*5;
        #pragma unroll
        for (int s=0;s<5;++s) pkey[gb + s] = b5[s];
    }

    if (bi == bj) return;   // diagonal: direct fold already covered all pairs

    __syncthreads();

    // ---- transposed fold: per j-row, top-5 over the 8 i-values this lane holds ----
    #pragma unroll
    for (int jf=0; jf<2; ++jf){
        #pragma unroll
        for (int q=0; q<4; ++q){
            unsigned int t5[5] = {0u,0u,0u,0u,0u};
            #pragma unroll
            for (int f=0; f<8; ++f){
                float v = acc[jf][f][q];
                int il = f*16 + l15;
                unsigned int u = __float_as_uint(v);
                unsigned int key = ((int)u < 0) ? ~u : (u | 0x80000000u);
                unsigned int pk = (key & 0xFFFFFF80u) | (unsigned int)(127 - il);
                if (pk > t5[4]){
                    t5[4] = pk;
                    #pragma unroll
                    for (int s=4;s>0;--s){
                        if (t5[s] > t5[s-1]){ unsigned int tp=t5[s]; t5[s]=t5[s-1]; t5[s-1]=tp; }
                    }
                }
            }
            int jl   = w*32 + jf*16 + l4*4 + q;
            int base = jl*80 + l15*5;
            #pragma unroll
            for (int s=0;s<5;++s) lists[base+s] = t5[s];
        }
    }
    __syncthreads();

    if (tid < 128){
        unsigned int b5[5] = {0u,0u,0u,0u,0u};
        int rb = tid*80;
        for (int c=0;c<80;++c){
            unsigned int pk = lists[rb + c];
            if (pk > b5[4]){
                b5[4] = pk;
                #pragma unroll
                for (int s=4;s>0;--s){
                    if (b5[s] > b5[s-1]){ unsigned int tp=b5[s]; b5[s]=b5[s-1]; b5[s-1]=tp; }
                }
            }
        }
        size_t gb = (size_t)(j0 + tid)*400 + (size_t)bi*5;
        #pragma unroll
        for (int s=0;s<5;++s) pkey[gb + s] = b5[s];
    }
}

// ---------------- kernel 5: select = merge(80 windows) + exact f32-chain refine ----------------
// One 64-thread block per row. Phase A: top-16 distinct candidates from pkey.
// Phase B: 4 lanes per candidate compute the exact f64 cos of f32 Xn, then the
// f32 A-chain key; 5 rounds of wave-argmax (key desc, idx asc) -> top-5 + dsum.
__global__ __launch_bounds__(64) void select_topk(const unsigned int* __restrict__ pkey,
    const float* __restrict__ Xn32, float* __restrict__ topA, int* __restrict__ topI,
    float* __restrict__ dinv)
{
    __shared__ unsigned int sk[400];
    __shared__ float xi[TD];
    __shared__ int cand[16];
    int row = blockIdx.x, l = threadIdx.x;
    const unsigned int* pr = &pkey[(size_t)row*400];
    for (int t = l; t < 400; t += 64) sk[t] = pr[t];
    for (int k = l; k < TD; k += 64) xi[k] = Xn32[(size_t)row*TD + k];
    __syncthreads();

    for (int s=0; s<16; ++s){
        unsigned int bk = 0u; int bj = 0x7fffffff; int bslot = -1;
        for (int t = l; t < 400; t += 64){
            unsigned int k = sk[t];
            int gj = (t/5)*128 + 127 - (int)(k & 127u);
            if (k > bk || (k == bk && gj < bj)){ bk = k; bj = gj; bslot = t; }
        }
        unsigned int v = bk; int ix = bj;
        #pragma unroll
        for (int off=32; off>0; off>>=1){
            unsigned int ov = (unsigned int)__shfl_xor((int)v, off);
            int oj = __shfl_xor(ix, off);
            if (ov > v || (ov == v && oj < ix)){ v = ov; ix = oj; }
        }
        if (l == 0) cand[s] = ix;
        if (bk == v && bj == ix && bslot >= 0) sk[bslot] = 0u;  // unique winner clears its slot
        __syncthreads();
    }

    // phase B: 16 candidates x 4 lanes; each lane dots 64 of 256 dims in f64
    int c = l >> 2, p = l & 3;
    int j  = cand[c];
    int jc = j < N_NODES ? j : 0;
    const float* xj = &Xn32[(size_t)jc*TD + p*64];
    const float* xr = &xi[p*64];
    double s = 0.0;
    for (int k = 0; k < 64; k += 4){
        float4 b = *(const float4*)(&xj[k]);
        float4 a = *(const float4*)(&xr[k]);
        s += (double)a.x*(double)b.x;
        s += (double)a.y*(double)b.y;
        s += (double)a.z*(double)b.z;
        s += (double)a.w*(double)b.w;
    }
    s += __shfl_xor(s, 1);
    s += __shfl_xor(s, 2);   // all 4 lanes of the group now hold the full dot

    float cos32 = (float)s;
    cos32 = fminf(fmaxf(cos32, -1.0f), 1.0f);
    float sam = acosf(cos32);
    float e   = expf(-0.2f*sam);
    float key = 1.0f/(1.0f + expf(-e));   // sigmoid; > 0.5 so clip(0.1) is a no-op
    if (j >= N_NODES) key = -1.0f;        // padded rows can never be selected

    double dsum = 0.0;
    for (int t = 0; t < TOPK; ++t){
        float v = key; int ix = j;
        #pragma unroll
        for (int off=32; off>0; off>>=1){
            float ov = __shfl_xor(v, off);
            int oix  = __shfl_xor(ix, off);
            if (ov > v || (ov == v && oix < ix)){ v = ov; ix = oix; }
        }
        dsum += (double)v;
        if (l == 0){ topA[row*TOPK + t] = v; topI[row*TOPK + t] = ix; }
        if (j == ix) key = -1.0f;  // all 4 dup lanes of the winner clear
    }
    if (l == 0) dinv[row] = (float)(1.0/sqrt(dsum));
}

// ---------------- kernel 6a (fused, G in ws): zero A row + out + scatter ----------------
__global__ __launch_bounds__(256) void finalize(const float* __restrict__ G,
    const float* __restrict__ topA, const int* __restrict__ topI,
    const float* __restrict__ dinv, float* __restrict__ out, float* __restrict__ Aout)
{
    __shared__ float w[TOPK];
    __shared__ int   jj[TOPK];
    __shared__ float av[TOPK];
    int row = blockIdx.x, tid = threadIdx.x;
    if (tid < TOPK){
        int j = topI[row*TOPK + tid];
        float a = topA[row*TOPK + tid];
        jj[tid] = j;
        av[tid] = a;
        w[tid]  = a * dinv[row] * dinv[j];
    }
    __syncthreads();

    float4* rowp = (float4*)(Aout + (size_t)row*N_NODES);
    const float4 z = {0.f,0.f,0.f,0.f};
    #pragma unroll
    for (int p = 0; p < 10; ++p){
        int c = p*256 + tid;
        if (c < 2500) rowp[c] = z;
    }

    for (int col = tid; col < OD; col += 256){
        float acc = 0.f;
        #pragma unroll
        for (int m=0;m<TOPK;++m) acc = fmaf(w[m], G[(size_t)jj[m]*OD + col], acc);
        out[(size_t)row*OD + col] = acc >= 0.f ? acc : 0.01f*acc;
    }

    __syncthreads();   // all zero-stores of this row done before the scatter
    if (tid < TOPK)
        Aout[(size_t)row*N_NODES + jj[tid]] = av[tid];
}

// ---------------- kernel 6b (fallback): out = lrelu( A_hat(5-sparse) @ G ) ----------------
__global__ __launch_bounds__(256) void outk(const float* __restrict__ G,
    const float* __restrict__ topA, const int* __restrict__ topI,
    const float* __restrict__ dinv, float* __restrict__ out)
{
    __shared__ float w[TOPK];
    __shared__ int   jj[TOPK];
    int row = blockIdx.x, tid = threadIdx.x;
    if (tid < TOPK){
        int j = topI[row*TOPK + tid];
        jj[tid] = j;
        w[tid]  = topA[row*TOPK + tid] * dinv[row] * dinv[j];
    }
    __syncthreads();
    for (int col = tid; col < OD; col += 256){
        float acc = 0.f;
        #pragma unroll
        for (int m=0;m<TOPK;++m) acc = fmaf(w[m], G[(size_t)jj[m]*OD + col], acc);
        out[(size_t)row*OD + col] = acc >= 0.f ? acc : 0.01f*acc;
    }
}

// ---------------- kernel 7b (fallback): zero the A row + scatter its 5 values ----------------
__global__ __launch_bounds__(256) void zero_scatter(const float* __restrict__ topA,
    const int* __restrict__ topI, float* __restrict__ Aout)
{
    int row = blockIdx.x;
    float4* rowp = (float4*)(Aout + (size_t)row*N_NODES);
    const float4 z = {0.f,0.f,0.f,0.f};
    int tid = threadIdx.x;
    #pragma unroll
    for (int p = 0; p < 10; ++p){
        int c = p*256 + tid;
        if (c < 2500) rowp[c] = z;
    }
    __syncthreads();
    if (tid < TOPK)
        Aout[(size_t)row*N_NODES + topI[row*TOPK + tid]] = topA[row*TOPK + tid];
}

extern "C" void kernel_launch(void* const* d_in, const int* in_sizes, int n_in,
                              void* d_out, int out_size, void* d_ws, size_t ws_size,
                              hipStream_t stream)
{
    const float* H   = (const float*)d_in[0];
    const float* gam = (const float*)d_in[1];
    const float* bet = (const float*)d_in[2];
    const float* Wt  = (const float*)d_in[3];
    const float* bt  = (const float*)d_in[4];
    const float* Wo  = (const float*)d_in[5];
    const float* bo  = (const float*)d_in[6];

    float* out  = (float*)d_out;
    float* Aout = out + (size_t)N_NODES*OD;   // + 7,000,000 floats

    // scratch carved out of the A region of d_out (all consumed before the A overwrite)
    float*          Xn32  = Aout;                               // 10240*256 f   = 2,621,440 f
    unsigned short* Xh    = (unsigned short*)(Aout + 2621440);  // 10240*256 us  = 1,310,720 f
    unsigned short* Hn16  = (unsigned short*)(Aout + 3932160);  // 10048*160 us  =   803,840 f
    unsigned short* WoT16 = (unsigned short*)(Aout + 4736000);  // 704*160 us    =    56,320 f
    float*          G_A   = Aout + 4792320;                     // 10000*700     = 7,000,000 f
    unsigned int*   pkey  = (unsigned int*)(Aout + 11792320);   // 10240*400     = 4,096,000 u
    double*         bn_part = (double*)(Aout + 15888320);       // 125*288 f64   =    72,000 f
    // ends at ~15.96M floats < 100,000,000

    // persistent scratch in ws (needed after the A overwrite)
    double* bn_stats = (double*)d_ws;             // 288 f64 = 576 f
    float*  topA  = (float*)d_ws + 576;           // 50,000 f32
    int*    topI  = (int*)((float*)d_ws + 50576); // 50,000 i32
    float*  dinvp = (float*)d_ws + 100576;        // 10,000 f32
    float*  G_ws  = (float*)d_ws + 110576;        // 7,000,000 f32 (if it fits)

    const size_t wsNeed = (size_t)(110576 + 7000000) * 4;   // ~28.4 MB
    const bool gInWs = (ws_size >= wsNeed);
    float* G = gInWs ? G_ws : G_A;

    bn_partial  <<<125, 192, 0, stream>>>(H, bn_part);
    bn_finish   <<<1, 320, 0, stream>>>(bn_part, bn_stats);
    theta_kernel<<<NPAD2/4, 256, 0, stream>>>(H, gam, bet, Wt, bt, bn_stats, Wo, WoT16,
                                              Xn32, Xh, Hn16);
    gproj       <<<157, 256, 0, stream>>>(Hn16, WoT16, bo, G);
    cos_blk     <<<3240, 256, 0, stream>>>(Xh, pkey);
    select_topk <<<N_NODES, 64, 0, stream>>>(pkey, Xn32, topA, topI, dinvp);
    if (gInWs){
        finalize    <<<N_NODES, 256, 0, stream>>>(G, topA, topI, dinvp, out, Aout);
    } else {
        outk        <<<N_NODES, 256, 0, stream>>>(G, topA, topI, dinvp, out);
        zero_scatter<<<N_NODES, 256, 0, stream>>>(topA, topI, Aout);
    }
}

// Round 10
// 353.416 us; speedup vs baseline: 4.6611x; 1.1296x over previous
//
#include <hip/hip_runtime.h>
#include <hip/hip_bf16.h>
#include <math.h>

#define N_NODES 10000
#define NPAD2   10240     // padded row count for the cos GEMM
#define IN_DIM  144
#define TD      256
#define OD      700
#define TOPK    5
#define GK      160       // padded K for gproj (144 -> 160)
#define GLD     168       // padded LDS row stride (shorts) for gproj tiles
#define LDT     72        // padded LDS row stride (shorts) for cos tiles

// dead-region zeroing, fused into cos_blk (floats [ZOFF, 100M) of the A matrix)
#define ZOFF   15960320u          // after all scratch (pkey/bn_part end here)
#define Z4TOT  21009920u          // (100,000,000 - ZOFF) / 4 float4s
#define Z4PB   38908u             // per zero-block (540 blocks)

typedef __attribute__((ext_vector_type(8))) short short8v;
typedef __attribute__((ext_vector_type(4))) float f32x4;

__device__ inline unsigned short f32_to_bf16_rne(float f){
    unsigned int u = __float_as_uint(f);
    unsigned int r = u + 0x7fffu + ((u >> 16) & 1u);
    return (unsigned short)(r >> 16);
}

// ---------------- kernel 1: BN partial sums (f64, deterministic) ----------------
__global__ void bn_partial(const float* __restrict__ H, double* __restrict__ part){
    int c = threadIdx.x;
    int b = blockIdx.x;
    if (c >= IN_DIM) return;
    int r0 = b * 80;
    double s = 0.0, q = 0.0;
    #pragma unroll 4
    for (int r = r0; r < r0 + 80; ++r){
        double v = (double)H[r*IN_DIM + c];
        s += v; q += v*v;
    }
    part[b*288 + c]       = s;
    part[b*288 + 144 + c] = q;
}

__global__ void bn_finish(const double* __restrict__ part, double* __restrict__ stats){
    int c = threadIdx.x;
    if (c >= 288) return;
    double s = 0.0;
    for (int b = 0; b < 125; ++b) s += part[b*288 + c];
    stats[c] = s;
}

// ---------------- kernel 2: BN + theta projection + row normalize (+ fused Wo conv) ----------------
__global__ __launch_bounds__(256) void theta_kernel(
    const float* __restrict__ H, const float* __restrict__ gam, const float* __restrict__ bet,
    const float* __restrict__ Wt, const float* __restrict__ bt, const double* __restrict__ stats,
    const float* __restrict__ Wo, unsigned short* __restrict__ WoT16,
    float* __restrict__ Xn32, unsigned short* __restrict__ Xh, unsigned short* __restrict__ Hn16)
{
    __shared__ double hn[4][IN_DIM];
    __shared__ double red[4][4];
    __shared__ double invs[4];
    int tid = threadIdx.x;
    int r0 = blockIdx.x * 4;

    // fused wconv: blocks 0..703 each convert one Wo row -> WoT16 [704][160] bf16
    if (blockIdx.x < 704 && tid < GK){
        int jj = blockIdx.x;
        float v = (jj < OD && tid < IN_DIM) ? Wo[tid*OD + jj] : 0.0f;
        WoT16[(size_t)jj*GK + tid] = f32_to_bf16_rne(v);
    }

    if (tid < GK){
        int c = tid;
        bool real = (c < IN_DIM);
        double mean = 0.0, scale = 0.0, bb = 0.0;
        if (real){
            mean  = stats[c] * (1.0/10000.0);
            double var = stats[144+c] * (1.0/10000.0) - mean*mean;
            scale = (1.0/sqrt(var + 1e-5)) * (double)gam[c];
            bb    = (double)bet[c];
        }
        for (int r = 0; r < 4; ++r){
            int row = r0 + r;
            float vf = 0.0f;
            if (real && row < N_NODES)
                vf = (float)(((double)H[row*IN_DIM + c] - mean)*scale + bb);
            if (row < 10048) Hn16[(size_t)row*GK + c] = f32_to_bf16_rne(vf);
            if (real) hn[r][c] = (double)vf;   // f32-rounded value, widened
        }
    }
    __syncthreads();

    int j = tid; // 0..255 == THETA_DIM
    double a0,a1,a2,a3;
    a0=a1=a2=a3=(double)bt[j];
    for (int k = 0; k < IN_DIM; ++k){
        double w = (double)Wt[k*TD + j];
        a0 += hn[0][k]*w; a1 += hn[1][k]*w; a2 += hn[2][k]*w; a3 += hn[3][k]*w;
    }
    float hx0=(float)a0, hx1=(float)a1, hx2=(float)a2, hx3=(float)a3;
    double n0=(double)hx0*(double)hx0, n1=(double)hx1*(double)hx1,
           n2=(double)hx2*(double)hx2, n3=(double)hx3*(double)hx3;
    #pragma unroll
    for (int off=32; off>0; off>>=1){
        n0 += __shfl_down(n0, off);
        n1 += __shfl_down(n1, off);
        n2 += __shfl_down(n2, off);
        n3 += __shfl_down(n3, off);
    }
    int lane = tid & 63, wave = tid >> 6;
    if (lane == 0){ red[0][wave]=n0; red[1][wave]=n1; red[2][wave]=n2; red[3][wave]=n3; }
    __syncthreads();
    if (tid < 4){
        double s = red[tid][0]+red[tid][1]+red[tid][2]+red[tid][3];
        invs[tid] = 1.0 / fmax(sqrt(s), 1e-12);
    }
    __syncthreads();

    float hx[4] = {hx0,hx1,hx2,hx3};
    #pragma unroll
    for (int r = 0; r < 4; ++r){
        int row = r0 + r;
        float xn = 0.0f;
        if (row < N_NODES) xn = (float)((double)hx[r]*invs[r]);
        Xn32[(size_t)row*TD + j] = xn;
        Xh  [(size_t)row*TD + j] = f32_to_bf16_rne(xn);
    }
}

// ---------------- kernel 3: G = Hn @ W_out + b_out  (bf16 MFMA) ----------------
__global__ __launch_bounds__(256,2) void gproj(const unsigned short* __restrict__ Hn16,
    const unsigned short* __restrict__ WoT16, const float* __restrict__ bo,
    float* __restrict__ G)
{
    __shared__ short Al[64*GLD];        // 21504 B
    __shared__ short Wl[2][64*GLD];     // 2 x 21504 B
    int tid = threadIdx.x;
    int w = tid >> 6, lane = tid & 63;
    int l15 = lane & 15, l4 = lane >> 4;
    int i0 = blockIdx.x * 64;

    int sr = tid >> 2, sc = tid & 3;
    #pragma unroll
    for (int p = 0; p < 5; ++p){
        int cb = sc + (p<<2);
        *(short8v*)(&Al[sr*GLD + cb*8]) =
            *(const short8v*)(&Hn16[(size_t)(i0+sr)*GK + cb*8]);
    }
    #pragma unroll
    for (int p = 0; p < 5; ++p){
        int cb = sc + (p<<2);
        *(short8v*)(&Wl[0][sr*GLD + cb*8]) =
            *(const short8v*)(&WoT16[(size_t)sr*GK + cb*8]);
    }
    __syncthreads();

    for (int jt = 0; jt < 11; ++jt){
        int cur = jt & 1;
        bool pf = (jt < 10);
        short8v g[5];
        if (pf){
            #pragma unroll
            for (int p = 0; p < 5; ++p){
                int cb = sc + (p<<2);
                g[p] = *(const short8v*)(&WoT16[(size_t)((jt+1)*64 + sr)*GK + cb*8]);
            }
        }
        f32x4 acc[4];
        #pragma unroll
        for (int n=0;n<4;++n) acc[n] = (f32x4){0.f,0.f,0.f,0.f};
        #pragma unroll
        for (int ks = 0; ks < 5; ++ks){
            short8v af = *(const short8v*)(&Al[(w*16 + l15)*GLD + ks*32 + l4*8]);
            #pragma unroll
            for (int n=0;n<4;++n){
                short8v bf = *(const short8v*)(&Wl[cur][(n*16 + l15)*GLD + ks*32 + l4*8]);
                acc[n] = __builtin_amdgcn_mfma_f32_16x16x32_bf16(af, bf, acc[n], 0, 0, 0);
            }
        }
        #pragma unroll
        for (int n=0;n<4;++n){
            int jcol = jt*64 + n*16 + l15;
            if (jcol < OD){
                float b = bo[jcol];
                #pragma unroll
                for (int q=0;q<4;++q){
                    int irow = i0 + w*16 + l4*4 + q;
                    if (irow < N_NODES)
                        G[(size_t)irow*OD + jcol] = acc[n][q] + b;
                }
            }
        }
        if (pf){
            #pragma unroll
            for (int p = 0; p < 5; ++p){
                int cb = sc + (p<<2);
                *(short8v*)(&Wl[cur^1][sr*GLD + cb*8]) = g[p];
            }
        }
        __syncthreads();
    }
}

// ---------------- kernel 4: symmetric cos Gram (upper triangle) + interleaved A-zeroing ----------------
// Grid = 540 groups x 7 blocks: bid%7==6 -> zero-block (streams 336 MB of dead-A zeros
// under the compute blocks' MFMA); else compute block (bijective -> 3240 triangle tiles).
// Compute: K staged with register prefetch (loads for kc+1 issued before MFMA of kc).
__global__ __launch_bounds__(256,3) void cos_blk(const unsigned short* __restrict__ Xh,
                                                 unsigned int* __restrict__ pkey,
                                                 float4* __restrict__ zb)
{
    __shared__ unsigned int smem[10240];   // 40960 B (tiles / lists union)

    int bid = blockIdx.x;
    int grp = bid / 7, ph = bid % 7;
    if (ph == 6){
        // pure zero block: fill a slice of the dead A region
        const float4 z = {0.f,0.f,0.f,0.f};
        size_t base = (size_t)grp * Z4PB;
        for (unsigned int i = threadIdx.x; i < Z4PB; i += 256){
            size_t idx = base + i;
            if (idx < Z4TOT) zb[idx] = z;
        }
        return;
    }

    short* Al = (short*)smem;              // [128][72]  i-rows
    short* Bl = ((short*)smem) + 128*LDT;  // [128][72]  j-rows

    // decode upper-triangle pair (bi <= bj) from compute index
    int t = grp*6 + ph;                    // 0..3239
    int bi = 0, rem = t;
    while (rem >= 80 - bi){ rem -= 80 - bi; ++bi; }
    int bj = bi + rem;
    int i0 = bi * 128;
    int j0 = bj * 128;

    int tid = threadIdx.x;
    int w = tid >> 6, lane = tid & 63;
    int l15 = lane & 15, l4 = lane >> 4;

    f32x4 acc[2][8];
    #pragma unroll
    for (int jf=0;jf<2;++jf){
        #pragma unroll
        for (int f=0;f<8;++f) acc[jf][f] = (f32x4){0.f,0.f,0.f,0.f};
    }

    int str = tid >> 3;     // 0..31 (row in group of 32)
    int scb = tid & 7;      // 0..7  (8-short col block)

    // stage kc=0
    {
        short8v ga[4], gb[4];
        #pragma unroll
        for (int p=0;p<4;++p){
            int r = p*32 + str;
            ga[p] = *(const short8v*)(&Xh[(size_t)(i0+r)*TD + scb*8]);
            gb[p] = *(const short8v*)(&Xh[(size_t)(j0+r)*TD + scb*8]);
        }
        #pragma unroll
        for (int p=0;p<4;++p){
            int r = p*32 + str;
            *(short8v*)(&Al[r*LDT + scb*8]) = ga[p];
            *(short8v*)(&Bl[r*LDT + scb*8]) = gb[p];
        }
    }
    __syncthreads();

    for (int kc = 0; kc < 4; ++kc){
        // prefetch next k-chunk into registers (in flight across the MFMA phase)
        short8v na[4], nb[4];
        if (kc < 3){
            int kn = (kc+1)*64;
            #pragma unroll
            for (int p=0;p<4;++p){
                int r = p*32 + str;
                na[p] = *(const short8v*)(&Xh[(size_t)(i0+r)*TD + kn + scb*8]);
                nb[p] = *(const short8v*)(&Xh[(size_t)(j0+r)*TD + kn + scb*8]);
            }
        }
        // MFMA phase over the staged chunk
        #pragma unroll
        for (int ks=0; ks<2; ++ks){
            short8v af0 = *(const short8v*)(&Bl[(w*32 +  0 + l15)*LDT + ks*32 + l4*8]);
            short8v af1 = *(const short8v*)(&Bl[(w*32 + 16 + l15)*LDT + ks*32 + l4*8]);
            #pragma unroll
            for (int f=0; f<8; ++f){
                short8v bf = *(const short8v*)(&Al[(f*16 + l15)*LDT + ks*32 + l4*8]);
                acc[0][f] = __builtin_amdgcn_mfma_f32_16x16x32_bf16(af0, bf, acc[0][f], 0,0,0);
                acc[1][f] = __builtin_amdgcn_mfma_f32_16x16x32_bf16(af1, bf, acc[1][f], 0,0,0);
            }
        }
        __syncthreads();            // all reads of LDS done
        if (kc < 3){
            #pragma unroll
            for (int p=0;p<4;++p){
                int r = p*32 + str;
                *(short8v*)(&Al[r*LDT + scb*8]) = na[p];
                *(short8v*)(&Bl[r*LDT + scb*8]) = nb[p];
            }
            __syncthreads();        // LDS ready for next MFMA phase
        }
    }
    __syncthreads();

    unsigned int* lists = smem;            // [128][80]

    // ---- direct fold: per i-column, top-5 over the 8 j-values this lane holds ----
    #pragma unroll
    for (int f=0; f<8; ++f){
        unsigned int t5[5] = {0u,0u,0u,0u,0u};
        #pragma unroll
        for (int jf=0; jf<2; ++jf){
            #pragma unroll
            for (int q=0; q<4; ++q){
                float v = acc[jf][f][q];
                int jl = w*32 + jf*16 + l4*4 + q;
                unsigned int u = __float_as_uint(v);
                unsigned int key = ((int)u < 0) ? ~u : (u | 0x80000000u);
                unsigned int pk = (key & 0xFFFFFF80u) | (unsigned int)(127 - jl);
                if (pk > t5[4]){
                    t5[4] = pk;
                    #pragma unroll
                    for (int s=4;s>0;--s){
                        if (t5[s] > t5[s-1]){ unsigned int tp=t5[s]; t5[s]=t5[s-1]; t5[s-1]=tp; }
                    }
                }
            }
        }
        int row  = f*16 + l15;
        int base = row*80 + (w*4 + l4)*5;
        #pragma unroll
        for (int s=0;s<5;++s) lists[base+s] = t5[s];
    }
    __syncthreads();

    if (tid < 128){
        unsigned int b5[5] = {0u,0u,0u,0u,0u};
        int rb = tid*80;
        for (int c=0;c<80;++c){
            unsigned int pk = lists[rb + c];
            if (pk > b5[4]){
                b5[4] = pk;
                #pragma unroll
                for (int s=4;s>0;--s){
                    if (b5[s] > b5[s-1]){ unsigned int tp=b5[s]; b5[s]=b5[s-1]; b5[s-1]=tp; }
                }
            }
        }
        size_t gb = (size_t)(i0 + tid)*400 + (size_t)bj*5;
        #pragma unroll
        for (int s=0;s<5;++s) pkey[gb + s] = b5[s];
    }

    if (bi == bj) return;   // diagonal: direct fold already covered all pairs

    __syncthreads();

    // ---- transposed fold: per j-row, top-5 over the 8 i-values this lane holds ----
    #pragma unroll
    for (int jf=0; jf<2; ++jf){
        #pragma unroll
        for (int q=0; q<4; ++q){
            unsigned int t5[5] = {0u,0u,0u,0u,0u};
            #pragma unroll
            for (int f=0; f<8; ++f){
                float v = acc[jf][f][q];
                int il = f*16 + l15;
                unsigned int u = __float_as_uint(v);
                unsigned int key = ((int)u < 0) ? ~u : (u | 0x80000000u);
                unsigned int pk = (key & 0xFFFFFF80u) | (unsigned int)(127 - il);
                if (pk > t5[4]){
                    t5[4] = pk;
                    #pragma unroll
                    for (int s=4;s>0;--s){
                        if (t5[s] > t5[s-1]){ unsigned int tp=t5[s]; t5[s]=t5[s-1]; t5[s-1]=tp; }
                    }
                }
            }
            int jl   = w*32 + jf*16 + l4*4 + q;
            int base = jl*80 + l15*5;
            #pragma unroll
            for (int s=0;s<5;++s) lists[base+s] = t5[s];
        }
    }
    __syncthreads();

    if (tid < 128){
        unsigned int b5[5] = {0u,0u,0u,0u,0u};
        int rb = tid*80;
        for (int c=0;c<80;++c){
            unsigned int pk = lists[rb + c];
            if (pk > b5[4]){
                b5[4] = pk;
                #pragma unroll
                for (int s=4;s>0;--s){
                    if (b5[s] > b5[s-1]){ unsigned int tp=b5[s]; b5[s]=b5[s-1]; b5[s-1]=tp; }
                }
            }
        }
        size_t gb = (size_t)(j0 + tid)*400 + (size_t)bi*5;
        #pragma unroll
        for (int s=0;s<5;++s) pkey[gb + s] = b5[s];
    }
}

// ---------------- kernel 5: select = merge(80 windows) + exact f32-chain refine ----------------
__global__ __launch_bounds__(64) void select_topk(const unsigned int* __restrict__ pkey,
    const float* __restrict__ Xn32, float* __restrict__ topA, int* __restrict__ topI,
    float* __restrict__ dinv)
{
    __shared__ unsigned int sk[400];
    __shared__ float xi[TD];
    __shared__ int cand[16];
    int row = blockIdx.x, l = threadIdx.x;
    const unsigned int* pr = &pkey[(size_t)row*400];
    for (int t = l; t < 400; t += 64) sk[t] = pr[t];
    for (int k = l; k < TD; k += 64) xi[k] = Xn32[(size_t)row*TD + k];
    __syncthreads();

    for (int s=0; s<16; ++s){
        unsigned int bk = 0u; int bj = 0x7fffffff; int bslot = -1;
        for (int t = l; t < 400; t += 64){
            unsigned int k = sk[t];
            int gj = (t/5)*128 + 127 - (int)(k & 127u);
            if (k > bk || (k == bk && gj < bj)){ bk = k; bj = gj; bslot = t; }
        }
        unsigned int v = bk; int ix = bj;
        #pragma unroll
        for (int off=32; off>0; off>>=1){
            unsigned int ov = (unsigned int)__shfl_xor((int)v, off);
            int oj = __shfl_xor(ix, off);
            if (ov > v || (ov == v && oj < ix)){ v = ov; ix = oj; }
        }
        if (l == 0) cand[s] = ix;
        if (bk == v && bj == ix && bslot >= 0) sk[bslot] = 0u;  // unique winner clears its slot
        __syncthreads();
    }

    // phase B: 16 candidates x 4 lanes; each lane dots 64 of 256 dims in f64
    int c = l >> 2, p = l & 3;
    int j  = cand[c];
    int jc = j < N_NODES ? j : 0;
    const float* xj = &Xn32[(size_t)jc*TD + p*64];
    const float* xr = &xi[p*64];
    double s = 0.0;
    for (int k = 0; k < 64; k += 4){
        float4 b = *(const float4*)(&xj[k]);
        float4 a = *(const float4*)(&xr[k]);
        s += (double)a.x*(double)b.x;
        s += (double)a.y*(double)b.y;
        s += (double)a.z*(double)b.z;
        s += (double)a.w*(double)b.w;
    }
    s += __shfl_xor(s, 1);
    s += __shfl_xor(s, 2);   // all 4 lanes of the group now hold the full dot

    float cos32 = (float)s;
    cos32 = fminf(fmaxf(cos32, -1.0f), 1.0f);
    float sam = acosf(cos32);
    float e   = expf(-0.2f*sam);
    float key = 1.0f/(1.0f + expf(-e));   // sigmoid; > 0.5 so clip(0.1) is a no-op
    if (j >= N_NODES) key = -1.0f;        // padded rows can never be selected

    double dsum = 0.0;
    for (int t = 0; t < TOPK; ++t){
        float v = key; int ix = j;
        #pragma unroll
        for (int off=32; off>0; off>>=1){
            float ov = __shfl_xor(v, off);
            int oix  = __shfl_xor(ix, off);
            if (ov > v || (ov == v && oix < ix)){ v = ov; ix = oix; }
        }
        dsum += (double)v;
        if (l == 0){ topA[row*TOPK + t] = v; topI[row*TOPK + t] = ix; }
        if (j == ix) key = -1.0f;  // all 4 dup lanes of the winner clear
    }
    if (l == 0) dinv[row] = (float)(1.0/sqrt(dsum));
}

// ---------------- kernel 6a (fused, G in ws): zero scratch-stripe rows + out + scatter ----------------
// Rows >= 1600 were already zeroed by cos_blk's interleaved zero blocks.
__global__ __launch_bounds__(256) void finalize(const float* __restrict__ G,
    const float* __restrict__ topA, const int* __restrict__ topI,
    const float* __restrict__ dinv, float* __restrict__ out, float* __restrict__ Aout)
{
    __shared__ float w[TOPK];
    __shared__ int   jj[TOPK];
    __shared__ float av[TOPK];
    int row = blockIdx.x, tid = threadIdx.x;
    if (tid < TOPK){
        int j = topI[row*TOPK + tid];
        float a = topA[row*TOPK + tid];
        jj[tid] = j;
        av[tid] = a;
        w[tid]  = a * dinv[row] * dinv[j];
    }
    __syncthreads();

    if (row < 1600){
        float4* rowp = (float4*)(Aout + (size_t)row*N_NODES);
        const float4 z = {0.f,0.f,0.f,0.f};
        #pragma unroll
        for (int p = 0; p < 10; ++p){
            int c = p*256 + tid;
            if (c < 2500) rowp[c] = z;
        }
    }

    for (int col = tid; col < OD; col += 256){
        float acc = 0.f;
        #pragma unroll
        for (int m=0;m<TOPK;++m) acc = fmaf(w[m], G[(size_t)jj[m]*OD + col], acc);
        out[(size_t)row*OD + col] = acc >= 0.f ? acc : 0.01f*acc;
    }

    __syncthreads();   // all zero-stores of this row done before the scatter
    if (tid < TOPK)
        Aout[(size_t)row*N_NODES + jj[tid]] = av[tid];
}

// ---------------- kernel 6b (fallback): out = lrelu( A_hat(5-sparse) @ G ) ----------------
__global__ __launch_bounds__(256) void outk(const float* __restrict__ G,
    const float* __restrict__ topA, const int* __restrict__ topI,
    const float* __restrict__ dinv, float* __restrict__ out)
{
    __shared__ float w[TOPK];
    __shared__ int   jj[TOPK];
    int row = blockIdx.x, tid = threadIdx.x;
    if (tid < TOPK){
        int j = topI[row*TOPK + tid];
        jj[tid] = j;
        w[tid]  = topA[row*TOPK + tid] * dinv[row] * dinv[j];
    }
    __syncthreads();
    for (int col = tid; col < OD; col += 256){
        float acc = 0.f;
        #pragma unroll
        for (int m=0;m<TOPK;++m) acc = fmaf(w[m], G[(size_t)jj[m]*OD + col], acc);
        out[(size_t)row*OD + col] = acc >= 0.f ? acc : 0.01f*acc;
    }
}

// ---------------- kernel 7b (fallback): zero scratch-stripe rows + scatter ----------------
__global__ __launch_bounds__(256) void zero_scatter(const float* __restrict__ topA,
    const int* __restrict__ topI, float* __restrict__ Aout)
{
    int row = blockIdx.x;
    int tid = threadIdx.x;
    if (row < 1600){
        float4* rowp = (float4*)(Aout + (size_t)row*N_NODES);
        const float4 z = {0.f,0.f,0.f,0.f};
        #pragma unroll
        for (int p = 0; p < 10; ++p){
            int c = p*256 + tid;
            if (c < 2500) rowp[c] = z;
        }
    }
    __syncthreads();
    if (tid < TOPK)
        Aout[(size_t)row*N_NODES + topI[row*TOPK + tid]] = topA[row*TOPK + tid];
}

extern "C" void kernel_launch(void* const* d_in, const int* in_sizes, int n_in,
                              void* d_out, int out_size, void* d_ws, size_t ws_size,
                              hipStream_t stream)
{
    const float* H   = (const float*)d_in[0];
    const float* gam = (const float*)d_in[1];
    const float* bet = (const float*)d_in[2];
    const float* Wt  = (const float*)d_in[3];
    const float* bt  = (const float*)d_in[4];
    const float* Wo  = (const float*)d_in[5];
    const float* bo  = (const float*)d_in[6];

    float* out  = (float*)d_out;
    float* Aout = out + (size_t)N_NODES*OD;   // + 7,000,000 floats

    // scratch carved out of the A region of d_out (all below ZOFF = 15,960,320 floats)
    float*          Xn32  = Aout;                               // 10240*256 f   = 2,621,440 f
    unsigned short* Xh    = (unsigned short*)(Aout + 2621440);  // 10240*256 us  = 1,310,720 f
    unsigned short* Hn16  = (unsigned short*)(Aout + 3932160);  // 10048*160 us  =   803,840 f
    unsigned short* WoT16 = (unsigned short*)(Aout + 4736000);  // 704*160 us    =    56,320 f
    float*          G_A   = Aout + 4792320;                     // 10000*700     = 7,000,000 f
    unsigned int*   pkey  = (unsigned int*)(Aout + 11792320);   // 10240*400     = 4,096,000 u
    double*         bn_part = (double*)(Aout + 15888320);       // 125*288 f64   =    72,000 f
    // scratch ends exactly at ZOFF = 15,960,320

    // persistent scratch in ws (needed after the A overwrite)
    double* bn_stats = (double*)d_ws;             // 288 f64 = 576 f
    float*  topA  = (float*)d_ws + 576;           // 50,000 f32
    int*    topI  = (int*)((float*)d_ws + 50576); // 50,000 i32
    float*  dinvp = (float*)d_ws + 100576;        // 10,000 f32
    float*  G_ws  = (float*)d_ws + 110576;        // 7,000,000 f32 (if it fits)

    const size_t wsNeed = (size_t)(110576 + 7000000) * 4;   // ~28.4 MB
    const bool gInWs = (ws_size >= wsNeed);
    float* G = gInWs ? G_ws : G_A;

    float4* zb = (float4*)(Aout + ZOFF);

    bn_partial  <<<125, 192, 0, stream>>>(H, bn_part);
    bn_finish   <<<1, 320, 0, stream>>>(bn_part, bn_stats);
    theta_kernel<<<NPAD2/4, 256, 0, stream>>>(H, gam, bet, Wt, bt, bn_stats, Wo, WoT16,
                                              Xn32, Xh, Hn16);
    gproj       <<<157, 256, 0, stream>>>(Hn16, WoT16, bo, G);
    cos_blk     <<<3780, 256, 0, stream>>>(Xh, pkey, zb);
    select_topk <<<N_NODES, 64, 0, stream>>>(pkey, Xn32, topA, topI, dinvp);
    if (gInWs){
        finalize    <<<N_NODES, 256, 0, stream>>>(G, topA, topI, dinvp, out, Aout);
    } else {
        outk        <<<N_NODES, 256, 0, stream>>>(G, topA, topI, dinvp, out);
        zero_scatter<<<N_NODES, 256, 0, stream>>>(topA, topI, Aout);
    }
}